// Round 1
// baseline (930.009 us; speedup 1.0000x reference)
//
#include <hip/hip_runtime.h>
#include <stdint.h>
#include <math.h>

#define HFM 64
#define WFM 128
#define CFM 128
#define BN 2
#define HWFM (HFM*WFM)          // 8192
#define NPIX (BN*HWFM)          // 16384
#define KQ 6000
#define NNEG 60
#define NE (NPIX*NNEG)          // 983040
#define EHALF_U 491520u
#define MSHIFT 15.0f

// ---------------- JAX threefry2x32 (bit-exact) ----------------
__host__ __device__ __forceinline__ void threefry2x32(uint32_t k0, uint32_t k1,
                                                      uint32_t x0, uint32_t x1,
                                                      uint32_t* o0, uint32_t* o1) {
  uint32_t ks2 = k0 ^ k1 ^ 0x1BD11BDAu;
  x0 += k0; x1 += k1;
#define TFR(r) { x0 += x1; x1 = (x1 << (r)) | (x1 >> (32 - (r))); x1 ^= x0; }
  TFR(13) TFR(15) TFR(26) TFR(6)
  x0 += k1;  x1 += ks2 + 1u;
  TFR(17) TFR(29) TFR(16) TFR(24)
  x0 += ks2; x1 += k0 + 2u;
  TFR(13) TFR(15) TFR(26) TFR(6)
  x0 += k0;  x1 += k1 + 3u;
  TFR(17) TFR(29) TFR(16) TFR(24)
  x0 += k1;  x1 += ks2 + 4u;
  TFR(13) TFR(15) TFR(26) TFR(6)
  x0 += ks2; x1 += k0 + 5u;
#undef TFR
  *o0 = x0; *o1 = x1;
}

// grid_sample coordinate: t is the pre-(2g-1) grid value; follows reference op order.
__device__ __forceinline__ void gs_coord(float t, float halfdim, float maxc,
                                         int* i0, int* i1, float* w) {
  float g = 2.0f * t - 1.0f;
  float x = (g + 1.0f) * halfdim - 0.5f;
  x = fminf(fmaxf(x, 0.0f), maxc);
  float f = floorf(x);
  *i0 = (int)f;
  *w = x - f;
  *i1 = (int)fminf(f + 1.0f, maxc);
}

__global__ void k_initS(float* __restrict__ S) {
  int i = blockIdx.x * 256 + threadIdx.x;
  if (i < NPIX) S[i] = 0.0f;
}

// [b,c,hw] -> [b,hw,c] for both ref and tgt. grid: (hw/32, c/32, 4) block (32,8)
__global__ void k_transpose(const float* __restrict__ ref, const float* __restrict__ tgt,
                            float* __restrict__ refT, float* __restrict__ tgtT) {
  __shared__ float tile[32][33];
  int z = blockIdx.z;
  int arr = z >> 1, b = z & 1;
  const float* src = (arr == 0 ? ref : tgt) + (size_t)b * CFM * HWFM;
  float* dst = (arr == 0 ? refT : tgtT) + (size_t)b * HWFM * CFM;
  int x0 = blockIdx.x * 32;   // hw
  int y0 = blockIdx.y * 32;   // c
  int tx = threadIdx.x, ty = threadIdx.y;
#pragma unroll
  for (int i = 0; i < 32; i += 8)
    tile[ty + i][tx] = src[(size_t)(y0 + ty + i) * HWFM + x0 + tx];
  __syncthreads();
#pragma unroll
  for (int i = 0; i < 32; i += 8)
    dst[(size_t)(x0 + ty + i) * CFM + (y0 + tx)] = tile[tx][ty + i];
}

// normalize each row of QT (length 128) in place
__global__ void k_normq(float* __restrict__ QT) {
  int p = blockIdx.x, c = threadIdx.x;
  float v = QT[p * CFM + c];
  float ss = v * v;
#pragma unroll
  for (int off = 32; off; off >>= 1) ss += __shfl_down(ss, off, 64);
  __shared__ float s2[2];
  if ((c & 63) == 0) s2[c >> 6] = ss;
  __syncthreads();
  float inv = 1.0f / fmaxf(sqrtf(s2[0] + s2[1]), 1e-12f);
  QT[p * CFM + c] = v * inv;
}

__global__ void k_qnorms(const float* __restrict__ queue, float* __restrict__ qInv) {
  int k = blockIdx.x * 256 + threadIdx.x;
  if (k >= KQ) return;
  float ss = 0.0f;
  for (int c = 0; c < CFM; c++) { float v = queue[c * KQ + k]; ss += v * v; }
  qInv[k] = 1.0f / fmaxf(sqrtf(ss), 1e-12f);
}

// per pixel: mask, l_pos, x_right. one block (128 threads = c) per pixel.
__global__ void k_prelude(const float* __restrict__ target_l, const float* __restrict__ target_r,
                          const float* __restrict__ QT, const float* __restrict__ tgtT,
                          float* __restrict__ S, float* __restrict__ logit0,
                          float* __restrict__ maskArr, float* __restrict__ xr) {
  int p = blockIdx.x;
  int c = threadIdx.x;
  int b = p >> 13;
  int rem = p & (HWFM - 1);
  int i = rem >> 7, j = rem & 127;
  const float stepx = 1.0f / 127.0f, stepy = 1.0f / 63.0f;
  float xb = (j == 127) ? 1.0f : j * stepx;
  float yb = (i == 63) ? 1.0f : i * stepy;
  const float* tl = target_l + (size_t)b * 256 * 512;
  const float* tr = target_r + (size_t)b * 256 * 512;
  float dl = tl[(4 * i) * 512 + 4 * j] * 0.25f;

  int y0i, y1i; float wy;
  gs_coord(yb, 32.0f, 63.0f, &y0i, &y1i, &wy);
  float t = xb - dl * (1.0f / 128.0f);   // x grid value for positive AND outer warp
  int x0i, x1i; float wx;
  gs_coord(t, 64.0f, 127.0f, &x0i, &x1i, &wx);

  // inner warp (index ramp warped by disps_r) evaluated at integer (y,x)
  auto innerv = [&](int y, int x) -> float {
    float xbx = (x == 127) ? 1.0f : x * stepx;
    float drv = tr[(4 * y) * 512 + 4 * x] * 0.25f;
    float ti = xbx + drv * (1.0f / 128.0f);
    float g = 2.0f * ti - 1.0f;
    float ix2 = fminf(fmaxf((g + 1.0f) * 64.0f - 0.5f, 0.0f), 127.0f);
    float x0f = floorf(ix2);
    float wxp = ix2 - x0f;
    float x1f = fminf(x0f + 1.0f, 127.0f);
    return x0f * (1.0f - wxp) + x1f * wxp;
  };
  float v00 = innerv(y0i, x0i), v01 = innerv(y0i, x1i);
  float v10 = innerv(y1i, x0i), v11 = innerv(y1i, x1i);
  float l2r2l = v00 * (1.0f - wx) * (1.0f - wy) + v01 * wx * (1.0f - wy)
              + v10 * (1.0f - wx) * wy + v11 * wx * wy;
  bool masko = fabsf((float)j - l2r2l) < 3.0f;
  float mk = (masko && (dl > 0.0f) && (t >= 0.0f)) ? 1.0f : 0.0f;

  // positive sample dot
  float w00 = (1.0f - wx) * (1.0f - wy), w01 = wx * (1.0f - wy);
  float w10 = (1.0f - wx) * wy,          w11 = wx * wy;
  int bo = b * HWFM;
  const float* r00 = tgtT + (size_t)(bo + y0i * WFM + x0i) * CFM;
  const float* r01 = tgtT + (size_t)(bo + y0i * WFM + x1i) * CFM;
  const float* r10 = tgtT + (size_t)(bo + y1i * WFM + x0i) * CFM;
  const float* r11 = tgtT + (size_t)(bo + y1i * WFM + x1i) * CFM;
  float q = QT[(size_t)p * CFM + c];
  float v = w00 * r00[c] + w01 * r01[c] + w10 * r10[c] + w11 * r11[c];
  float dot = q * v, ss = v * v;
#pragma unroll
  for (int off = 32; off; off >>= 1) {
    dot += __shfl_down(dot, off, 64);
    ss  += __shfl_down(ss,  off, 64);
  }
  __shared__ float rd[2], rs[2];
  if ((c & 63) == 0) { rd[c >> 6] = dot; rs[c >> 6] = ss; }
  __syncthreads();
  if (c == 0) {
    float dt = rd[0] + rd[1], st = rs[0] + rs[1];
    float lpos = dt / fmaxf(sqrtf(st), 1e-12f);
    float lg0 = (lpos * mk) / 0.07f;
    logit0[p] = lg0;
    maskArr[p] = mk;
    xr[p] = t * 128.0f;
    atomicAdd(&S[p], expf(lg0 - MSHIFT));
  }
}

// one thread per (pixel, negative)
__global__ void k_negatives(const float* __restrict__ QT, const float* __restrict__ tgtT,
                            const float* __restrict__ maskArr, const float* __restrict__ xr,
                            float* __restrict__ S,
                            uint32_t k1a, uint32_t k1b, uint32_t k2a, uint32_t k2b) {
  int idx = blockIdx.x * 256 + threadIdx.x;
  if (idx >= NE) return;
  int p = idx / NNEG;
  uint32_t e = (uint32_t)idx;

  // randint(k1, 1, 25): higher/lower bits = two outputs of block (e, e+NE)
  uint32_t h0, h1;
  threefry2x32(k1a, k1b, e, e + (uint32_t)NE, &h0, &h1);
  uint32_t off = ((h0 % 24u) * 16u + (h1 % 24u)) % 24u;
  float mag = (float)(1u + off);

  // uniform(k2): one 32-bit draw
  uint32_t ub;
  {
    uint32_t a, bm;
    if (e < EHALF_U) { threefry2x32(k2a, k2b, e, e + EHALF_U, &a, &bm); ub = a; }
    else             { threefry2x32(k2a, k2b, e - EHALF_U, e, &a, &bm); ub = bm; }
  }
  float u = __uint_as_float((ub >> 9) | 0x3F800000u) - 1.0f;
  float sg = (u > 0.5f) ? 1.0f : ((u < 0.5f) ? -1.0f : 0.0f);

  float v = xr[p] + mag * sg;
  float r = fmodf(v, 128.0f);
  if (r < 0.0f) r += 128.0f;
  float fx = r * (1.0f / 128.0f);
  float fy = fx * (1.0f / 64.0f);

  int x0i, x1i, y0i, y1i; float wx, wy;
  gs_coord(fx, 64.0f, 127.0f, &x0i, &x1i, &wx);
  gs_coord(fy, 32.0f, 63.0f, &y0i, &y1i, &wy);
  float w00 = (1.0f - wx) * (1.0f - wy), w01 = wx * (1.0f - wy);
  float w10 = (1.0f - wx) * wy,          w11 = wx * wy;

  int b = p >> 13;
  int bo = b * HWFM;
  const float4* r00 = (const float4*)(tgtT + (size_t)(bo + y0i * WFM + x0i) * CFM);
  const float4* r01 = (const float4*)(tgtT + (size_t)(bo + y0i * WFM + x1i) * CFM);
  const float4* r10 = (const float4*)(tgtT + (size_t)(bo + y1i * WFM + x0i) * CFM);
  const float4* r11 = (const float4*)(tgtT + (size_t)(bo + y1i * WFM + x1i) * CFM);
  const float4* qv  = (const float4*)(QT + (size_t)p * CFM);

  float dot = 0.0f, ss = 0.0f;
#pragma unroll 8
  for (int cc = 0; cc < CFM / 4; cc++) {
    float4 a = r00[cc], bq = r01[cc], cq = r10[cc], dq = r11[cc], q4 = qv[cc];
    float vx = w00 * a.x + w01 * bq.x + w10 * cq.x + w11 * dq.x;
    float vy = w00 * a.y + w01 * bq.y + w10 * cq.y + w11 * dq.y;
    float vz = w00 * a.z + w01 * bq.z + w10 * cq.z + w11 * dq.z;
    float vw = w00 * a.w + w01 * bq.w + w10 * cq.w + w11 * dq.w;
    dot += q4.x * vx + q4.y * vy + q4.z * vz + q4.w * vw;
    ss  += vx * vx + vy * vy + vz * vz + vw * vw;
  }
  float ln = dot / fmaxf(sqrtf(ss), 1e-12f);
  float lg = (ln * maskArr[p]) / 0.07f;
  atomicAdd(&S[p], expf(lg - MSHIFT));
}

// fused l_q GEMM + exp-sum. tile: 64 pixels x 128 queue cols, 256 threads, 4x8 per thread.
#define BP 64
#define BKT 128
#define CK 16
__global__ __launch_bounds__(256) void k_gemm(const float* __restrict__ QT,
                                              const float* __restrict__ queue,
                                              const float* __restrict__ qInv,
                                              const float* __restrict__ maskArr,
                                              float* __restrict__ S) {
  __shared__ float As[CK][68];
  __shared__ float Bs[CK][BKT];
  __shared__ float Srow[BP];
  int tid = threadIdx.x;
  int k0 = blockIdx.x * BKT;
  int p0 = blockIdx.y * BP;
  int tk = tid & 15;   // cols tk*8 + kk
  int tp = tid >> 4;   // rows tp*4 + pp
  float acc[4][8];
#pragma unroll
  for (int a = 0; a < 4; a++)
#pragma unroll
    for (int bb = 0; bb < 8; bb++) acc[a][bb] = 0.0f;

  for (int c0 = 0; c0 < CFM; c0 += CK) {
    for (int l = tid; l < BP * CK; l += 256) {
      int rr = l >> 4, cc = l & 15;
      As[cc][rr] = QT[(size_t)(p0 + rr) * CFM + c0 + cc];
    }
    for (int l = tid; l < CK * BKT; l += 256) {
      int cc = l >> 7, kk = l & 127;
      int k = k0 + kk;
      Bs[cc][kk] = (k < KQ) ? queue[(size_t)(c0 + cc) * KQ + k] : 0.0f;
    }
    __syncthreads();
#pragma unroll
    for (int cc = 0; cc < CK; cc++) {
      float a[4], bb[8];
      *(float4*)&a[0]  = *(const float4*)&As[cc][tp * 4];
      *(float4*)&bb[0] = *(const float4*)&Bs[cc][tk * 8];
      *(float4*)&bb[4] = *(const float4*)&Bs[cc][tk * 8 + 4];
#pragma unroll
      for (int pp = 0; pp < 4; pp++)
#pragma unroll
        for (int kk = 0; kk < 8; kk++)
          acc[pp][kk] = fmaf(a[pp], bb[kk], acc[pp][kk]);
    }
    __syncthreads();
  }

  if (tid < BP) Srow[tid] = 0.0f;
  __syncthreads();
  float minv[4], rowsum[4] = {0.0f, 0.0f, 0.0f, 0.0f};
#pragma unroll
  for (int pp = 0; pp < 4; pp++) minv[pp] = maskArr[p0 + tp * 4 + pp];
#pragma unroll
  for (int kk = 0; kk < 8; kk++) {
    int k = k0 + tk * 8 + kk;
    if (k < KQ) {
      float qi = qInv[k];
#pragma unroll
      for (int pp = 0; pp < 4; pp++) {
        float lg = (acc[pp][kk] * qi * minv[pp]) / 0.07f;
        rowsum[pp] += expf(lg - MSHIFT);
      }
    }
  }
#pragma unroll
  for (int pp = 0; pp < 4; pp++) atomicAdd(&Srow[tp * 4 + pp], rowsum[pp]);
  __syncthreads();
  if (tid < BP) atomicAdd(&S[p0 + tid], Srow[tid]);
}

__global__ void k_finalize(const float* __restrict__ S, const float* __restrict__ logit0,
                           float* __restrict__ out) {
  int tid = threadIdx.x;
  double acc = 0.0;
  for (int p = tid; p < NPIX; p += 256)
    acc += (double)(logf(S[p]) + MSHIFT - logit0[p]);
#pragma unroll
  for (int off = 32; off; off >>= 1) acc += __shfl_down(acc, off, 64);
  __shared__ double sd[4];
  if ((tid & 63) == 0) sd[tid >> 6] = acc;
  __syncthreads();
  if (tid == 0) out[0] = (float)((sd[0] + sd[1] + sd[2] + sd[3]) / (double)NPIX);
}

extern "C" void kernel_launch(void* const* d_in, const int* in_sizes, int n_in,
                              void* d_out, int out_size, void* d_ws, size_t ws_size,
                              hipStream_t stream) {
  const float* ref   = (const float*)d_in[0];
  const float* tgt   = (const float*)d_in[1];
  const float* tl    = (const float*)d_in[2];
  const float* tr    = (const float*)d_in[3];
  const float* queue = (const float*)d_in[4];
  float* out = (float*)d_out;
  float* ws = (float*)d_ws;

  float* QT   = ws;                      // 2097152
  float* tgtT = ws + 2097152;            // 2097152
  float* qInv = ws + 4194304;            // 6000
  float* S    = ws + 4200304;            // 16384
  float* lg0  = ws + 4216688;            // 16384
  float* mk   = ws + 4233072;            // 16384
  float* xr   = ws + 4249456;            // 16384

  // JAX: k1, k2 = split(key(1234))  — key data (0, 1234)
  uint32_t b0o0, b0o1, b1o0, b1o1;
  threefry2x32(0u, 1234u, 0u, 2u, &b0o0, &b0o1);
  threefry2x32(0u, 1234u, 1u, 3u, &b1o0, &b1o1);
  uint32_t k1a = b0o0, k1b = b1o0, k2a = b0o1, k2b = b1o1;

  k_initS<<<dim3(NPIX / 256), dim3(256), 0, stream>>>(S);
  k_transpose<<<dim3(HWFM / 32, CFM / 32, 4), dim3(32, 8), 0, stream>>>(ref, tgt, QT, tgtT);
  k_normq<<<dim3(NPIX), dim3(128), 0, stream>>>(QT);
  k_qnorms<<<dim3((KQ + 255) / 256), dim3(256), 0, stream>>>(queue, qInv);
  k_prelude<<<dim3(NPIX), dim3(128), 0, stream>>>(tl, tr, QT, tgtT, S, lg0, mk, xr);
  k_negatives<<<dim3(NE / 256), dim3(256), 0, stream>>>(QT, tgtT, mk, xr, S, k1a, k1b, k2a, k2b);
  k_gemm<<<dim3((KQ + BKT - 1) / BKT, NPIX / BP), dim3(256), 0, stream>>>(QT, queue, qInv, mk, S);
  k_finalize<<<dim3(1), dim3(256), 0, stream>>>(S, lg0, out);
}

// Round 2
// 595.464 us; speedup vs baseline: 1.5618x; 1.5618x over previous
//
#include <hip/hip_runtime.h>
#include <stdint.h>
#include <math.h>

#define HFM 64
#define WFM 128
#define CFM 128
#define BN 2
#define HWFM (HFM*WFM)          // 8192
#define NPIX (BN*HWFM)          // 16384
#define KQ 6000
#define KQPAD 6016
#define NNEG 60
#define NE (NPIX*NNEG)          // 983040
#define EHALF_U 491520u
#define MSHIFT 15.0f

typedef __bf16 bf16_8 __attribute__((ext_vector_type(8)));
typedef float f32_4 __attribute__((ext_vector_type(4)));

// ---------------- JAX threefry2x32 (bit-exact) ----------------
__host__ __device__ __forceinline__ void threefry2x32(uint32_t k0, uint32_t k1,
                                                      uint32_t x0, uint32_t x1,
                                                      uint32_t* o0, uint32_t* o1) {
  uint32_t ks2 = k0 ^ k1 ^ 0x1BD11BDAu;
  x0 += k0; x1 += k1;
#define TFR(r) { x0 += x1; x1 = (x1 << (r)) | (x1 >> (32 - (r))); x1 ^= x0; }
  TFR(13) TFR(15) TFR(26) TFR(6)
  x0 += k1;  x1 += ks2 + 1u;
  TFR(17) TFR(29) TFR(16) TFR(24)
  x0 += ks2; x1 += k0 + 2u;
  TFR(13) TFR(15) TFR(26) TFR(6)
  x0 += k0;  x1 += k1 + 3u;
  TFR(17) TFR(29) TFR(16) TFR(24)
  x0 += k1;  x1 += ks2 + 4u;
  TFR(13) TFR(15) TFR(26) TFR(6)
  x0 += ks2; x1 += k0 + 5u;
#undef TFR
  *o0 = x0; *o1 = x1;
}

__device__ __forceinline__ uint16_t f2bf(float x) {
  uint32_t u = __float_as_uint(x);
  uint32_t r = (u + 0x7FFFu + ((u >> 16) & 1u)) >> 16;
  return (uint16_t)r;
}

// grid_sample coordinate helper (reference op order)
__device__ __forceinline__ void gs_coord(float t, float halfdim, float maxc,
                                         int* i0, int* i1, float* w) {
  float g = 2.0f * t - 1.0f;
  float x = (g + 1.0f) * halfdim - 0.5f;
  x = fminf(fmaxf(x, 0.0f), maxc);
  float f = floorf(x);
  *i0 = (int)f;
  *w = x - f;
  *i1 = (int)fminf(f + 1.0f, maxc);
}

__global__ void k_initS(float* __restrict__ S) {
  int i = blockIdx.x * 256 + threadIdx.x;
  if (i < NPIX) S[i] = 0.0f;
}

// [b,c,hw] -> [b,hw,c] for both ref and tgt. grid: (hw/32, c/32, 4) block (32,8)
__global__ void k_transpose(const float* __restrict__ ref, const float* __restrict__ tgt,
                            float* __restrict__ refT, float* __restrict__ tgtT) {
  __shared__ float tile[32][33];
  int z = blockIdx.z;
  int arr = z >> 1, b = z & 1;
  const float* src = (arr == 0 ? ref : tgt) + (size_t)b * CFM * HWFM;
  float* dst = (arr == 0 ? refT : tgtT) + (size_t)b * HWFM * CFM;
  int x0 = blockIdx.x * 32;   // hw
  int y0 = blockIdx.y * 32;   // c
  int tx = threadIdx.x, ty = threadIdx.y;
#pragma unroll
  for (int i = 0; i < 32; i += 8)
    tile[ty + i][tx] = src[(size_t)(y0 + ty + i) * HWFM + x0 + tx];
  __syncthreads();
#pragma unroll
  for (int i = 0; i < 32; i += 8)
    dst[(size_t)(x0 + ty + i) * CFM + (y0 + tx)] = tile[tx][ty + i];
}

// transpose queue [128][6000] fp32 -> [6016][128] bf16 (rows 6000..6015 zero)
__global__ void k_qtrans(const float* __restrict__ queue, uint16_t* __restrict__ queueTbf) {
  __shared__ float tile[32][33];
  int n0 = blockIdx.x * 32;   // queue col
  int c0 = blockIdx.y * 32;   // channel
  int tx = threadIdx.x, ty = threadIdx.y;
#pragma unroll
  for (int i = 0; i < 32; i += 8) {
    int n = n0 + tx;
    tile[ty + i][tx] = (n < KQ) ? queue[(size_t)(c0 + ty + i) * KQ + n] : 0.0f;
  }
  __syncthreads();
#pragma unroll
  for (int i = 0; i < 32; i += 8)
    queueTbf[(size_t)(n0 + ty + i) * CFM + (c0 + tx)] = f2bf(tile[tx][ty + i]);
}

// normalize each row of QT (length 128) in place + emit bf16 copy
__global__ void k_normq(float* __restrict__ QT, uint16_t* __restrict__ QTbf) {
  int p = blockIdx.x, c = threadIdx.x;
  float v = QT[p * CFM + c];
  float ss = v * v;
#pragma unroll
  for (int off = 32; off; off >>= 1) ss += __shfl_down(ss, off, 64);
  __shared__ float s2[2];
  if ((c & 63) == 0) s2[c >> 6] = ss;
  __syncthreads();
  float inv = 1.0f / fmaxf(sqrtf(s2[0] + s2[1]), 1e-12f);
  float nv = v * inv;
  QT[p * CFM + c] = nv;
  QTbf[p * CFM + c] = f2bf(nv);
}

__global__ void k_qnorms(const float* __restrict__ queue, float* __restrict__ qInv) {
  int k = blockIdx.x * 256 + threadIdx.x;
  if (k >= KQ) return;
  float ss = 0.0f;
  for (int c = 0; c < CFM; c++) { float v = queue[c * KQ + k]; ss += v * v; }
  qInv[k] = 1.0f / fmaxf(sqrtf(ss), 1e-12f);
}

// per pixel: mask, l_pos, x_right. one block (128 threads = c) per pixel.
__global__ void k_prelude(const float* __restrict__ target_l, const float* __restrict__ target_r,
                          const float* __restrict__ QT, const float* __restrict__ tgtT,
                          float* __restrict__ S, float* __restrict__ logit0,
                          float* __restrict__ maskArr, float* __restrict__ xr) {
  int p = blockIdx.x;
  int c = threadIdx.x;
  int b = p >> 13;
  int rem = p & (HWFM - 1);
  int i = rem >> 7, j = rem & 127;
  const float stepx = 1.0f / 127.0f, stepy = 1.0f / 63.0f;
  float xb = (j == 127) ? 1.0f : j * stepx;
  float yb = (i == 63) ? 1.0f : i * stepy;
  const float* tl = target_l + (size_t)b * 256 * 512;
  const float* tr = target_r + (size_t)b * 256 * 512;
  float dl = tl[(4 * i) * 512 + 4 * j] * 0.25f;

  int y0i, y1i; float wy;
  gs_coord(yb, 32.0f, 63.0f, &y0i, &y1i, &wy);
  float t = xb - dl * (1.0f / 128.0f);
  int x0i, x1i; float wx;
  gs_coord(t, 64.0f, 127.0f, &x0i, &x1i, &wx);

  auto innerv = [&](int y, int x) -> float {
    float xbx = (x == 127) ? 1.0f : x * stepx;
    float drv = tr[(4 * y) * 512 + 4 * x] * 0.25f;
    float ti = xbx + drv * (1.0f / 128.0f);
    float g = 2.0f * ti - 1.0f;
    float ix2 = fminf(fmaxf((g + 1.0f) * 64.0f - 0.5f, 0.0f), 127.0f);
    float x0f = floorf(ix2);
    float wxp = ix2 - x0f;
    float x1f = fminf(x0f + 1.0f, 127.0f);
    return x0f * (1.0f - wxp) + x1f * wxp;
  };
  float v00 = innerv(y0i, x0i), v01 = innerv(y0i, x1i);
  float v10 = innerv(y1i, x0i), v11 = innerv(y1i, x1i);
  float l2r2l = v00 * (1.0f - wx) * (1.0f - wy) + v01 * wx * (1.0f - wy)
              + v10 * (1.0f - wx) * wy + v11 * wx * wy;
  bool masko = fabsf((float)j - l2r2l) < 3.0f;
  float mk = (masko && (dl > 0.0f) && (t >= 0.0f)) ? 1.0f : 0.0f;

  float w00 = (1.0f - wx) * (1.0f - wy), w01 = wx * (1.0f - wy);
  float w10 = (1.0f - wx) * wy,          w11 = wx * wy;
  int bo = b * HWFM;
  const float* r00 = tgtT + (size_t)(bo + y0i * WFM + x0i) * CFM;
  const float* r01 = tgtT + (size_t)(bo + y0i * WFM + x1i) * CFM;
  const float* r10 = tgtT + (size_t)(bo + y1i * WFM + x0i) * CFM;
  const float* r11 = tgtT + (size_t)(bo + y1i * WFM + x1i) * CFM;
  float q = QT[(size_t)p * CFM + c];
  float v = w00 * r00[c] + w01 * r01[c] + w10 * r10[c] + w11 * r11[c];
  float dot = q * v, ss = v * v;
#pragma unroll
  for (int off = 32; off; off >>= 1) {
    dot += __shfl_down(dot, off, 64);
    ss  += __shfl_down(ss,  off, 64);
  }
  __shared__ float rd[2], rs[2];
  if ((c & 63) == 0) { rd[c >> 6] = dot; rs[c >> 6] = ss; }
  __syncthreads();
  if (c == 0) {
    float dt = rd[0] + rd[1], st = rs[0] + rs[1];
    float lpos = dt / fmaxf(sqrtf(st), 1e-12f);
    float lg0 = (lpos * mk) / 0.07f;
    logit0[p] = lg0;
    maskArr[p] = mk;
    xr[p] = t * 128.0f;
    atomicAdd(&S[p], expf(lg0 - MSHIFT));
  }
}

// one thread per (pixel, negative)
__global__ void k_negatives(const float* __restrict__ QT, const float* __restrict__ tgtT,
                            const float* __restrict__ maskArr, const float* __restrict__ xr,
                            float* __restrict__ S,
                            uint32_t k1a, uint32_t k1b, uint32_t k2a, uint32_t k2b) {
  int idx = blockIdx.x * 256 + threadIdx.x;
  if (idx >= NE) return;
  int p = idx / NNEG;
  uint32_t e = (uint32_t)idx;

  uint32_t h0, h1;
  threefry2x32(k1a, k1b, e, e + (uint32_t)NE, &h0, &h1);
  uint32_t off = ((h0 % 24u) * 16u + (h1 % 24u)) % 24u;
  float mag = (float)(1u + off);

  uint32_t ub;
  {
    uint32_t a, bm;
    if (e < EHALF_U) { threefry2x32(k2a, k2b, e, e + EHALF_U, &a, &bm); ub = a; }
    else             { threefry2x32(k2a, k2b, e - EHALF_U, e, &a, &bm); ub = bm; }
  }
  float u = __uint_as_float((ub >> 9) | 0x3F800000u) - 1.0f;
  float sg = (u > 0.5f) ? 1.0f : ((u < 0.5f) ? -1.0f : 0.0f);

  float v = xr[p] + mag * sg;
  float r = fmodf(v, 128.0f);
  if (r < 0.0f) r += 128.0f;
  float fx = r * (1.0f / 128.0f);
  float fy = fx * (1.0f / 64.0f);

  int x0i, x1i, y0i, y1i; float wx, wy;
  gs_coord(fx, 64.0f, 127.0f, &x0i, &x1i, &wx);
  gs_coord(fy, 32.0f, 63.0f, &y0i, &y1i, &wy);
  float w00 = (1.0f - wx) * (1.0f - wy), w01 = wx * (1.0f - wy);
  float w10 = (1.0f - wx) * wy,          w11 = wx * wy;

  int b = p >> 13;
  int bo = b * HWFM;
  const float4* r00 = (const float4*)(tgtT + (size_t)(bo + y0i * WFM + x0i) * CFM);
  const float4* r01 = (const float4*)(tgtT + (size_t)(bo + y0i * WFM + x1i) * CFM);
  const float4* r10 = (const float4*)(tgtT + (size_t)(bo + y1i * WFM + x0i) * CFM);
  const float4* r11 = (const float4*)(tgtT + (size_t)(bo + y1i * WFM + x1i) * CFM);
  const float4* qv  = (const float4*)(QT + (size_t)p * CFM);

  float dot = 0.0f, ss = 0.0f;
#pragma unroll 8
  for (int cc = 0; cc < CFM / 4; cc++) {
    float4 a = r00[cc], bq = r01[cc], cq = r10[cc], dq = r11[cc], q4 = qv[cc];
    float vx = w00 * a.x + w01 * bq.x + w10 * cq.x + w11 * dq.x;
    float vy = w00 * a.y + w01 * bq.y + w10 * cq.y + w11 * dq.y;
    float vz = w00 * a.z + w01 * bq.z + w10 * cq.z + w11 * dq.z;
    float vw = w00 * a.w + w01 * bq.w + w10 * cq.w + w11 * dq.w;
    dot += q4.x * vx + q4.y * vy + q4.z * vz + q4.w * vw;
    ss  += vx * vx + vy * vy + vz * vz + vw * vw;
  }
  float ln = dot / fmaxf(sqrtf(ss), 1e-12f);
  float lg = (ln * maskArr[p]) / 0.07f;
  atomicAdd(&S[p], expf(lg - MSHIFT));
}

// -------- MFMA l_q GEMM fused with exp-sum --------
// block = 256 threads = 4 waves in 2x2: block tile 64 p x 128 n.
// wave tile 32 p x 64 n = 2 mt x 4 nt 16x16 tiles, K=128 = 4 MFMA slices.
__global__ __launch_bounds__(256) void k_gemm_mfma(
    const uint16_t* __restrict__ QTbf,     // [NPIX][128] bf16
    const uint16_t* __restrict__ queueTbf, // [6016][128] bf16
    const float* __restrict__ qInv,        // [6000]
    const float* __restrict__ maskArr,
    float* __restrict__ S) {
  __shared__ float Srow[64];
  int tid = threadIdx.x;
  int wave = tid >> 6;
  int lane = tid & 63;
  int quad = lane >> 4;
  int l16 = lane & 15;
  int wm = wave >> 1;
  int wn = wave & 1;
  int p0 = blockIdx.y * 64 + wm * 32;
  int n0 = blockIdx.x * 128 + wn * 64;

  if (tid < 64) Srow[tid] = 0.0f;

  // A fragments: 2 mt x 4 ks
  bf16_8 Af[2][4];
  const uint16_t* arow = QTbf + (size_t)(p0 + l16) * CFM + quad * 8;
#pragma unroll
  for (int mt = 0; mt < 2; mt++)
#pragma unroll
    for (int ks = 0; ks < 4; ks++)
      Af[mt][ks] = *(const bf16_8*)(arow + (size_t)mt * 16 * CFM + ks * 32);

  // B fragments: 4 nt x 4 ks
  bf16_8 Bf[4][4];
  const uint16_t* brow = queueTbf + (size_t)(n0 + l16) * CFM + quad * 8;
#pragma unroll
  for (int nt = 0; nt < 4; nt++)
#pragma unroll
    for (int ks = 0; ks < 4; ks++)
      Bf[nt][ks] = *(const bf16_8*)(brow + (size_t)nt * 16 * CFM + ks * 32);

  f32_4 acc[2][4];
#pragma unroll
  for (int mt = 0; mt < 2; mt++)
#pragma unroll
    for (int nt = 0; nt < 4; nt++)
      acc[mt][nt] = (f32_4){0.0f, 0.0f, 0.0f, 0.0f};

#pragma unroll
  for (int ks = 0; ks < 4; ks++)
#pragma unroll
    for (int mt = 0; mt < 2; mt++)
#pragma unroll
      for (int nt = 0; nt < 4; nt++)
        acc[mt][nt] = __builtin_amdgcn_mfma_f32_16x16x32_bf16(Af[mt][ks], Bf[nt][ks], acc[mt][nt], 0, 0, 0);

  // epilogue: lg = acc * qInv[n] * mask[p] / T ; e = exp(lg - 15) ; row-sum
  float mrow[2][4];
#pragma unroll
  for (int mt = 0; mt < 2; mt++)
#pragma unroll
    for (int r = 0; r < 4; r++)
      mrow[mt][r] = maskArr[p0 + mt * 16 + quad * 4 + r] * (1.0f / 0.07f);

  float rowsum[2][4] = {{0.0f,0.0f,0.0f,0.0f},{0.0f,0.0f,0.0f,0.0f}};
#pragma unroll
  for (int nt = 0; nt < 4; nt++) {
    int n = n0 + nt * 16 + l16;
    bool valid = n < KQ;
    float qi = valid ? qInv[n] : 0.0f;
#pragma unroll
    for (int mt = 0; mt < 2; mt++)
#pragma unroll
      for (int r = 0; r < 4; r++) {
        float lg = acc[mt][nt][r] * qi * mrow[mt][r];
        float e = valid ? __expf(lg - MSHIFT) : 0.0f;
        rowsum[mt][r] += e;
      }
  }
  // reduce across the 16 lanes of each quad
#pragma unroll
  for (int mt = 0; mt < 2; mt++)
#pragma unroll
    for (int r = 0; r < 4; r++) {
      float v = rowsum[mt][r];
      v += __shfl_xor(v, 1);
      v += __shfl_xor(v, 2);
      v += __shfl_xor(v, 4);
      v += __shfl_xor(v, 8);
      rowsum[mt][r] = v;
    }
  __syncthreads();   // Srow init visible
  if (l16 == 0) {
#pragma unroll
    for (int mt = 0; mt < 2; mt++)
#pragma unroll
      for (int r = 0; r < 4; r++)
        atomicAdd(&Srow[wm * 32 + mt * 16 + quad * 4 + r], rowsum[mt][r]);
  }
  __syncthreads();
  if (tid < 64) atomicAdd(&S[blockIdx.y * 64 + tid], Srow[tid]);
}

__global__ void k_finalize(const float* __restrict__ S, const float* __restrict__ logit0,
                           float* __restrict__ out) {
  int tid = threadIdx.x;
  double acc = 0.0;
  for (int p = tid; p < NPIX; p += 256)
    acc += (double)(logf(S[p]) + MSHIFT - logit0[p]);
#pragma unroll
  for (int off = 32; off; off >>= 1) acc += __shfl_down(acc, off, 64);
  __shared__ double sd[4];
  if ((tid & 63) == 0) sd[tid >> 6] = acc;
  __syncthreads();
  if (tid == 0) out[0] = (float)((sd[0] + sd[1] + sd[2] + sd[3]) / (double)NPIX);
}

extern "C" void kernel_launch(void* const* d_in, const int* in_sizes, int n_in,
                              void* d_out, int out_size, void* d_ws, size_t ws_size,
                              hipStream_t stream) {
  const float* ref   = (const float*)d_in[0];
  const float* tgt   = (const float*)d_in[1];
  const float* tl    = (const float*)d_in[2];
  const float* tr    = (const float*)d_in[3];
  const float* queue = (const float*)d_in[4];
  float* out = (float*)d_out;
  float* ws = (float*)d_ws;

  float* QT   = ws;                          // 2097152 floats
  float* tgtT = ws + 2097152;                // 2097152
  float* qInv = ws + 4194304;                // 6016 (6000 used)
  float* S    = ws + 4200320;                // 16384
  float* lg0  = ws + 4216704;                // 16384
  float* mk   = ws + 4233088;                // 16384
  float* xr   = ws + 4249472;                // 16384
  uint16_t* QTbf     = (uint16_t*)(ws + 4265856);   // 16384*128 bf16 = 4 MB
  uint16_t* queueTbf = (uint16_t*)(ws + 5314432);   // 6016*128 bf16 = 1.5 MB

  // JAX: k1, k2 = split(key(1234))
  uint32_t b0o0, b0o1, b1o0, b1o1;
  threefry2x32(0u, 1234u, 0u, 2u, &b0o0, &b0o1);
  threefry2x32(0u, 1234u, 1u, 3u, &b1o0, &b1o1);
  uint32_t k1a = b0o0, k1b = b1o0, k2a = b0o1, k2b = b1o1;

  k_initS<<<dim3(NPIX / 256), dim3(256), 0, stream>>>(S);
  k_transpose<<<dim3(HWFM / 32, CFM / 32, 4), dim3(32, 8), 0, stream>>>(ref, tgt, QT, tgtT);
  k_qtrans<<<dim3((KQPAD) / 32, CFM / 32), dim3(32, 8), 0, stream>>>(queue, queueTbf);
  k_normq<<<dim3(NPIX), dim3(128), 0, stream>>>(QT, QTbf);
  k_qnorms<<<dim3((KQ + 255) / 256), dim3(256), 0, stream>>>(queue, qInv);
  k_prelude<<<dim3(NPIX), dim3(128), 0, stream>>>(tl, tr, QT, tgtT, S, lg0, mk, xr);
  k_negatives<<<dim3(NE / 256), dim3(256), 0, stream>>>(QT, tgtT, mk, xr, S, k1a, k1b, k2a, k2b);
  k_gemm_mfma<<<dim3(KQPAD / 128, NPIX / 64), dim3(256), 0, stream>>>(QTbf, queueTbf, qInv, mk, S);
  k_finalize<<<dim3(1), dim3(256), 0, stream>>>(S, lg0, out);
}

// Round 3
// 365.712 us; speedup vs baseline: 2.5430x; 1.6282x over previous
//
#include <hip/hip_runtime.h>
#include <stdint.h>
#include <math.h>

#define HFM 64
#define WFM 128
#define CFM 128
#define BN 2
#define HWFM (HFM*WFM)          // 8192
#define NPIX (BN*HWFM)          // 16384
#define KQ 6000
#define KQPAD 6016
#define NNEG 60
#define NE (NPIX*NNEG)          // 983040
#define EHALF_U 491520u
#define MSHIFT 15.0f

typedef _Float16 f16_8 __attribute__((ext_vector_type(8)));
typedef float f32_4 __attribute__((ext_vector_type(4)));

// ---------------- JAX threefry2x32 (bit-exact) ----------------
__host__ __device__ __forceinline__ void threefry2x32(uint32_t k0, uint32_t k1,
                                                      uint32_t x0, uint32_t x1,
                                                      uint32_t* o0, uint32_t* o1) {
  uint32_t ks2 = k0 ^ k1 ^ 0x1BD11BDAu;
  x0 += k0; x1 += k1;
#define TFR(r) { x0 += x1; x1 = (x1 << (r)) | (x1 >> (32 - (r))); x1 ^= x0; }
  TFR(13) TFR(15) TFR(26) TFR(6)
  x0 += k1;  x1 += ks2 + 1u;
  TFR(17) TFR(29) TFR(16) TFR(24)
  x0 += ks2; x1 += k0 + 2u;
  TFR(13) TFR(15) TFR(26) TFR(6)
  x0 += k0;  x1 += k1 + 3u;
  TFR(17) TFR(29) TFR(16) TFR(24)
  x0 += k1;  x1 += ks2 + 4u;
  TFR(13) TFR(15) TFR(26) TFR(6)
  x0 += ks2; x1 += k0 + 5u;
#undef TFR
  *o0 = x0; *o1 = x1;
}

// grid_sample coordinate helper (reference op order)
__device__ __forceinline__ void gs_coord(float t, float halfdim, float maxc,
                                         int* i0, int* i1, float* w) {
  float g = 2.0f * t - 1.0f;
  float x = (g + 1.0f) * halfdim - 0.5f;
  x = fminf(fmaxf(x, 0.0f), maxc);
  float f = floorf(x);
  *i0 = (int)f;
  *w = x - f;
  *i1 = (int)fminf(f + 1.0f, maxc);
}

__global__ void k_initS(float* __restrict__ S) {
  int i = blockIdx.x * 256 + threadIdx.x;
  if (i < NPIX) S[i] = 0.0f;
}

// ref [b,c,hw] -> QT fp32 [b,hw,c];  tgt [b,c,hw] -> tgtTf16 [b,hw,c] f16
__global__ void k_transpose(const float* __restrict__ ref, const float* __restrict__ tgt,
                            float* __restrict__ QT, _Float16* __restrict__ tgtTf16) {
  __shared__ float tile[32][33];
  int z = blockIdx.z;
  int arr = z >> 1, b = z & 1;
  const float* src = (arr == 0 ? ref : tgt) + (size_t)b * CFM * HWFM;
  int x0 = blockIdx.x * 32;   // hw
  int y0 = blockIdx.y * 32;   // c
  int tx = threadIdx.x, ty = threadIdx.y;
#pragma unroll
  for (int i = 0; i < 32; i += 8)
    tile[ty + i][tx] = src[(size_t)(y0 + ty + i) * HWFM + x0 + tx];
  __syncthreads();
  if (arr == 0) {
    float* dst = QT + (size_t)b * HWFM * CFM;
#pragma unroll
    for (int i = 0; i < 32; i += 8)
      dst[(size_t)(x0 + ty + i) * CFM + (y0 + tx)] = tile[tx][ty + i];
  } else {
    _Float16* dst = tgtTf16 + (size_t)b * HWFM * CFM;
#pragma unroll
    for (int i = 0; i < 32; i += 8)
      dst[(size_t)(x0 + ty + i) * CFM + (y0 + tx)] = (_Float16)tile[tx][ty + i];
  }
}

// transpose queue [128][6000] fp32 -> [6016][128] f16 (rows 6000..6015 zero)
__global__ void k_qtrans(const float* __restrict__ queue, _Float16* __restrict__ queueTf) {
  __shared__ float tile[32][33];
  int n0 = blockIdx.x * 32;   // queue col
  int c0 = blockIdx.y * 32;   // channel
  int tx = threadIdx.x, ty = threadIdx.y;
#pragma unroll
  for (int i = 0; i < 32; i += 8) {
    int n = n0 + tx;
    tile[ty + i][tx] = (n < KQ) ? queue[(size_t)(c0 + ty + i) * KQ + n] : 0.0f;
  }
  __syncthreads();
#pragma unroll
  for (int i = 0; i < 32; i += 8)
    queueTf[(size_t)(n0 + ty + i) * CFM + (c0 + tx)] = (_Float16)tile[tx][ty + i];
}

// normalize each row of QT (length 128) in place + emit f16 copy
__global__ void k_normq(float* __restrict__ QT, _Float16* __restrict__ QTf) {
  int p = blockIdx.x, c = threadIdx.x;
  float v = QT[p * CFM + c];
  float ss = v * v;
#pragma unroll
  for (int off = 32; off; off >>= 1) ss += __shfl_down(ss, off, 64);
  __shared__ float s2[2];
  if ((c & 63) == 0) s2[c >> 6] = ss;
  __syncthreads();
  float inv = 1.0f / fmaxf(sqrtf(s2[0] + s2[1]), 1e-12f);
  float nv = v * inv;
  QT[p * CFM + c] = nv;
  QTf[p * CFM + c] = (_Float16)nv;
}

__global__ void k_qnorms(const float* __restrict__ queue, float* __restrict__ qInv) {
  int k = blockIdx.x * 256 + threadIdx.x;
  if (k >= KQ) return;
  float ss = 0.0f;
  for (int c = 0; c < CFM; c++) { float v = queue[c * KQ + k]; ss += v * v; }
  qInv[k] = 1.0f / fmaxf(sqrtf(ss), 1e-12f);
}

// per pixel: mask, l_pos, x_right. one block (128 threads = c) per pixel.
__global__ void k_prelude(const float* __restrict__ target_l, const float* __restrict__ target_r,
                          const float* __restrict__ QT, const _Float16* __restrict__ tgtTf,
                          float* __restrict__ S, float* __restrict__ logit0,
                          float* __restrict__ maskArr, float* __restrict__ xr) {
  int p = blockIdx.x;
  int c = threadIdx.x;
  int b = p >> 13;
  int rem = p & (HWFM - 1);
  int i = rem >> 7, j = rem & 127;
  const float stepx = 1.0f / 127.0f, stepy = 1.0f / 63.0f;
  float xb = (j == 127) ? 1.0f : j * stepx;
  float yb = (i == 63) ? 1.0f : i * stepy;
  const float* tl = target_l + (size_t)b * 256 * 512;
  const float* tr = target_r + (size_t)b * 256 * 512;
  float dl = tl[(4 * i) * 512 + 4 * j] * 0.25f;

  int y0i, y1i; float wy;
  gs_coord(yb, 32.0f, 63.0f, &y0i, &y1i, &wy);
  float t = xb - dl * (1.0f / 128.0f);
  int x0i, x1i; float wx;
  gs_coord(t, 64.0f, 127.0f, &x0i, &x1i, &wx);

  auto innerv = [&](int y, int x) -> float {
    float xbx = (x == 127) ? 1.0f : x * stepx;
    float drv = tr[(4 * y) * 512 + 4 * x] * 0.25f;
    float ti = xbx + drv * (1.0f / 128.0f);
    float g = 2.0f * ti - 1.0f;
    float ix2 = fminf(fmaxf((g + 1.0f) * 64.0f - 0.5f, 0.0f), 127.0f);
    float x0f = floorf(ix2);
    float wxp = ix2 - x0f;
    float x1f = fminf(x0f + 1.0f, 127.0f);
    return x0f * (1.0f - wxp) + x1f * wxp;
  };
  float v00 = innerv(y0i, x0i), v01 = innerv(y0i, x1i);
  float v10 = innerv(y1i, x0i), v11 = innerv(y1i, x1i);
  float l2r2l = v00 * (1.0f - wx) * (1.0f - wy) + v01 * wx * (1.0f - wy)
              + v10 * (1.0f - wx) * wy + v11 * wx * wy;
  bool masko = fabsf((float)j - l2r2l) < 3.0f;
  float mk = (masko && (dl > 0.0f) && (t >= 0.0f)) ? 1.0f : 0.0f;

  float w00 = (1.0f - wx) * (1.0f - wy), w01 = wx * (1.0f - wy);
  float w10 = (1.0f - wx) * wy,          w11 = wx * wy;
  int bo = b * HWFM;
  const _Float16* r00 = tgtTf + (size_t)(bo + y0i * WFM + x0i) * CFM;
  const _Float16* r01 = tgtTf + (size_t)(bo + y0i * WFM + x1i) * CFM;
  const _Float16* r10 = tgtTf + (size_t)(bo + y1i * WFM + x0i) * CFM;
  const _Float16* r11 = tgtTf + (size_t)(bo + y1i * WFM + x1i) * CFM;
  float q = QT[(size_t)p * CFM + c];
  float v = w00 * (float)r00[c] + w01 * (float)r01[c]
          + w10 * (float)r10[c] + w11 * (float)r11[c];
  float dot = q * v, ss = v * v;
#pragma unroll
  for (int off = 32; off; off >>= 1) {
    dot += __shfl_down(dot, off, 64);
    ss  += __shfl_down(ss,  off, 64);
  }
  __shared__ float rd[2], rs[2];
  if ((c & 63) == 0) { rd[c >> 6] = dot; rs[c >> 6] = ss; }
  __syncthreads();
  if (c == 0) {
    float dt = rd[0] + rd[1], st = rs[0] + rs[1];
    float lpos = dt / fmaxf(sqrtf(st), 1e-12f);
    float lg0 = (lpos * mk) / 0.07f;
    logit0[p] = lg0;
    maskArr[p] = mk;
    xr[p] = t * 128.0f;
    atomicAdd(&S[p], expf(lg0 - MSHIFT));
  }
}

// -------- negatives: wave-per-pixel, MFMA reduction --------
// 256 threads = 4 waves = 4 pixels. Phase A: lane=negative RNG.
// Phase B: 4 groups of 16 negatives; lane(l16=neg, quad=ch-octet) builds
// f16 A-fragments from coalesced tgtTf16 reads; dot & norm via mfma f16.
__global__ __launch_bounds__(256) void k_negatives_mfma(
    const _Float16* __restrict__ QTf, const _Float16* __restrict__ tgtTf,
    const float* __restrict__ maskArr, const float* __restrict__ xr,
    float* __restrict__ S,
    uint32_t k1a, uint32_t k1b, uint32_t k2a, uint32_t k2b) {
  int tid = threadIdx.x;
  int wave = tid >> 6;
  int lane = tid & 63;
  int quad = lane >> 4;
  int l16 = lane & 15;
  int p = blockIdx.x * 4 + wave;
  int b = p >> 13;

  // ---- Phase A: per-lane RNG for negative n = lane ----
  uint32_t e = (uint32_t)(p * NNEG + lane);
  uint32_t h0, h1;
  threefry2x32(k1a, k1b, e, e + (uint32_t)NE, &h0, &h1);
  uint32_t off = ((h0 % 24u) * 16u + (h1 % 24u)) % 24u;
  float mag = (float)(1u + off);
  uint32_t ub;
  {
    uint32_t a, bm;
    if (e < EHALF_U) { threefry2x32(k2a, k2b, e, e + EHALF_U, &a, &bm); ub = a; }
    else             { threefry2x32(k2a, k2b, e - EHALF_U, e, &a, &bm); ub = bm; }
  }
  float u = __uint_as_float((ub >> 9) | 0x3F800000u) - 1.0f;
  float sg = (u > 0.5f) ? 1.0f : ((u < 0.5f) ? -1.0f : 0.0f);

  float xrp = xr[p];
  float v = xrp + mag * sg;
  float r = fmodf(v, 128.0f);
  if (r < 0.0f) r += 128.0f;
  float fx = r * (1.0f / 128.0f);
  float fy = fx * (1.0f / 64.0f);
  int x0i, x1i, y0i, y1i; float wx, wy;
  gs_coord(fx, 64.0f, 127.0f, &x0i, &x1i, &wx);
  gs_coord(fy, 32.0f, 63.0f, &y0i, &y1i, &wy);   // y0=0, y1=1 always here
  float w00 = (1.0f - wx) * (1.0f - wy), w01 = wx * (1.0f - wy);
  float w10 = (1.0f - wx) * wy,          w11 = wx * wy;

  // ---- Phase B ----
  float mask_p = maskArr[p] * (1.0f / 0.07f);
  const _Float16* qrow = QTf + (size_t)p * CFM;
  f16_8 Qf[4];
#pragma unroll
  for (int s = 0; s < 4; s++)
    Qf[s] = *(const f16_8*)(qrow + s * 32 + quad * 8);

  const _Float16* tb0 = tgtTf + (size_t)(b * HWFM) * CFM;        // y=0 rows
  const _Float16* tb1 = tgtTf + (size_t)(b * HWFM + WFM) * CFM;  // y=1 rows
  float esum = 0.0f;

#pragma unroll
  for (int g = 0; g < 4; g++) {
    int srcl = g * 16 + l16;
    float gw00 = __shfl(w00, srcl, 64);
    float gw01 = __shfl(w01, srcl, 64);
    float gw10 = __shfl(w10, srcl, 64);
    float gw11 = __shfl(w11, srcl, 64);
    int gx0 = __shfl(x0i, srcl, 64);
    int gx1 = __shfl(x1i, srcl, 64);
    const _Float16* r00 = tb0 + (size_t)gx0 * CFM;
    const _Float16* r01 = tb0 + (size_t)gx1 * CFM;
    const _Float16* r10 = tb1 + (size_t)gx0 * CFM;
    const _Float16* r11 = tb1 + (size_t)gx1 * CFM;

    f32_4 accD = (f32_4){0.0f, 0.0f, 0.0f, 0.0f};
    f32_4 accS = (f32_4){0.0f, 0.0f, 0.0f, 0.0f};
#pragma unroll
    for (int s = 0; s < 4; s++) {
      int ch = s * 32 + quad * 8;
      f16_8 a8 = *(const f16_8*)(r00 + ch);
      f16_8 b8 = *(const f16_8*)(r01 + ch);
      f16_8 c8 = *(const f16_8*)(r10 + ch);
      f16_8 d8 = *(const f16_8*)(r11 + ch);
      f16_8 vf;
#pragma unroll
      for (int jj = 0; jj < 8; jj++) {
        float vv = gw00 * (float)a8[jj] + gw01 * (float)b8[jj]
                 + gw10 * (float)c8[jj] + gw11 * (float)d8[jj];
        vf[jj] = (_Float16)vv;
      }
      accD = __builtin_amdgcn_mfma_f32_16x16x32_f16(vf, Qf[s], accD, 0, 0, 0);
      accS = __builtin_amdgcn_mfma_f32_16x16x32_f16(vf, vf, accS, 0, 0, 0);
    }
    // diagonal lanes: row (quad*4+reg) == col l16
    if ((l16 >> 2) == quad) {
      int rg = l16 & 3;
      int n_g = g * 16 + l16;
      if (n_g < NNEG) {
        float dot = accD[rg], ssn = accS[rg];
        float ln = dot / fmaxf(sqrtf(ssn), 1e-12f);
        float lg = ln * mask_p;
        esum += __expf(lg - MSHIFT);
      }
    }
  }
#pragma unroll
  for (int o = 32; o; o >>= 1) esum += __shfl_xor(esum, o, 64);
  if (lane == 0) atomicAdd(&S[p], esum);
}

// -------- MFMA l_q GEMM fused with exp-sum (f16) --------
__global__ __launch_bounds__(256) void k_gemm_mfma(
    const _Float16* __restrict__ QTf,     // [NPIX][128]
    const _Float16* __restrict__ queueTf, // [6016][128]
    const float* __restrict__ qInv,
    const float* __restrict__ maskArr,
    float* __restrict__ S) {
  __shared__ float Srow[64];
  int tid = threadIdx.x;
  int wave = tid >> 6;
  int lane = tid & 63;
  int quad = lane >> 4;
  int l16 = lane & 15;
  int wm = wave >> 1;
  int wn = wave & 1;
  int p0 = blockIdx.y * 64 + wm * 32;
  int n0 = blockIdx.x * 128 + wn * 64;

  if (tid < 64) Srow[tid] = 0.0f;

  f16_8 Af[2][4];
  const _Float16* arow = QTf + (size_t)(p0 + l16) * CFM + quad * 8;
#pragma unroll
  for (int mt = 0; mt < 2; mt++)
#pragma unroll
    for (int ks = 0; ks < 4; ks++)
      Af[mt][ks] = *(const f16_8*)(arow + (size_t)mt * 16 * CFM + ks * 32);

  f16_8 Bf[4][4];
  const _Float16* brow = queueTf + (size_t)(n0 + l16) * CFM + quad * 8;
#pragma unroll
  for (int nt = 0; nt < 4; nt++)
#pragma unroll
    for (int ks = 0; ks < 4; ks++)
      Bf[nt][ks] = *(const f16_8*)(brow + (size_t)nt * 16 * CFM + ks * 32);

  f32_4 acc[2][4];
#pragma unroll
  for (int mt = 0; mt < 2; mt++)
#pragma unroll
    for (int nt = 0; nt < 4; nt++)
      acc[mt][nt] = (f32_4){0.0f, 0.0f, 0.0f, 0.0f};

#pragma unroll
  for (int ks = 0; ks < 4; ks++)
#pragma unroll
    for (int mt = 0; mt < 2; mt++)
#pragma unroll
      for (int nt = 0; nt < 4; nt++)
        acc[mt][nt] = __builtin_amdgcn_mfma_f32_16x16x32_f16(Af[mt][ks], Bf[nt][ks], acc[mt][nt], 0, 0, 0);

  float mrow[2][4];
#pragma unroll
  for (int mt = 0; mt < 2; mt++)
#pragma unroll
    for (int r = 0; r < 4; r++)
      mrow[mt][r] = maskArr[p0 + mt * 16 + quad * 4 + r] * (1.0f / 0.07f);

  float rowsum[2][4] = {{0.0f,0.0f,0.0f,0.0f},{0.0f,0.0f,0.0f,0.0f}};
#pragma unroll
  for (int nt = 0; nt < 4; nt++) {
    int n = n0 + nt * 16 + l16;
    bool valid = n < KQ;
    float qi = valid ? qInv[n] : 0.0f;
#pragma unroll
    for (int mt = 0; mt < 2; mt++)
#pragma unroll
      for (int r = 0; r < 4; r++) {
        float lg = acc[mt][nt][r] * qi * mrow[mt][r];
        float ev = valid ? __expf(lg - MSHIFT) : 0.0f;
        rowsum[mt][r] += ev;
      }
  }
#pragma unroll
  for (int mt = 0; mt < 2; mt++)
#pragma unroll
    for (int r = 0; r < 4; r++) {
      float vv = rowsum[mt][r];
      vv += __shfl_xor(vv, 1);
      vv += __shfl_xor(vv, 2);
      vv += __shfl_xor(vv, 4);
      vv += __shfl_xor(vv, 8);
      rowsum[mt][r] = vv;
    }
  __syncthreads();
  if (l16 == 0) {
#pragma unroll
    for (int mt = 0; mt < 2; mt++)
#pragma unroll
      for (int r = 0; r < 4; r++)
        atomicAdd(&Srow[wm * 32 + mt * 16 + quad * 4 + r], rowsum[mt][r]);
  }
  __syncthreads();
  if (tid < 64) atomicAdd(&S[blockIdx.y * 64 + tid], Srow[tid]);
}

__global__ void k_finalize(const float* __restrict__ S, const float* __restrict__ logit0,
                           float* __restrict__ out) {
  int tid = threadIdx.x;
  double acc = 0.0;
  for (int p = tid; p < NPIX; p += 256)
    acc += (double)(logf(S[p]) + MSHIFT - logit0[p]);
#pragma unroll
  for (int off = 32; off; off >>= 1) acc += __shfl_down(acc, off, 64);
  __shared__ double sd[4];
  if ((tid & 63) == 0) sd[tid >> 6] = acc;
  __syncthreads();
  if (tid == 0) out[0] = (float)((sd[0] + sd[1] + sd[2] + sd[3]) / (double)NPIX);
}

extern "C" void kernel_launch(void* const* d_in, const int* in_sizes, int n_in,
                              void* d_out, int out_size, void* d_ws, size_t ws_size,
                              hipStream_t stream) {
  const float* ref   = (const float*)d_in[0];
  const float* tgt   = (const float*)d_in[1];
  const float* tl    = (const float*)d_in[2];
  const float* tr    = (const float*)d_in[3];
  const float* queue = (const float*)d_in[4];
  float* out = (float*)d_out;
  float* ws = (float*)d_ws;

  float* QT   = ws;                          // [NPIX][128] fp32  (2097152)
  float* qInv = ws + 2097152;                // 6016
  float* S    = ws + 2103168;                // 16384
  float* lg0  = ws + 2119552;                // 16384
  float* mk   = ws + 2135936;                // 16384
  float* xr   = ws + 2152320;                // 16384 -> ends 2168704
  _Float16* QTf     = (_Float16*)(ws + 2168704);   // NPIX*128 f16  (1048576 fl)
  _Float16* queueTf = (_Float16*)(ws + 3217280);   // 6016*128 f16  (385024 fl)
  _Float16* tgtTf   = (_Float16*)(ws + 3602304);   // NPIX*128 f16  (1048576 fl)

  // JAX: k1, k2 = split(key(1234))
  uint32_t b0o0, b0o1, b1o0, b1o1;
  threefry2x32(0u, 1234u, 0u, 2u, &b0o0, &b0o1);
  threefry2x32(0u, 1234u, 1u, 3u, &b1o0, &b1o1);
  uint32_t k1a = b0o0, k1b = b1o0, k2a = b0o1, k2b = b1o1;

  k_initS<<<dim3(NPIX / 256), dim3(256), 0, stream>>>(S);
  k_transpose<<<dim3(HWFM / 32, CFM / 32, 4), dim3(32, 8), 0, stream>>>(ref, tgt, QT, tgtTf);
  k_qtrans<<<dim3(KQPAD / 32, CFM / 32), dim3(32, 8), 0, stream>>>(queue, queueTf);
  k_normq<<<dim3(NPIX), dim3(128), 0, stream>>>(QT, QTf);
  k_qnorms<<<dim3((KQ + 255) / 256), dim3(256), 0, stream>>>(queue, qInv);
  k_prelude<<<dim3(NPIX), dim3(128), 0, stream>>>(tl, tr, QT, tgtTf, S, lg0, mk, xr);
  k_negatives_mfma<<<dim3(NPIX / 4), dim3(256), 0, stream>>>(QTf, tgtTf, mk, xr, S, k1a, k1b, k2a, k2b);
  k_gemm_mfma<<<dim3(KQPAD / 128, NPIX / 64), dim3(256), 0, stream>>>(QTf, queueTf, qInv, mk, S);
  k_finalize<<<dim3(1), dim3(256), 0, stream>>>(S, lg0, out);
}

// Round 4
// 301.905 us; speedup vs baseline: 3.0805x; 1.2114x over previous
//
#include <hip/hip_runtime.h>
#include <stdint.h>
#include <math.h>

#define HFM 64
#define WFM 128
#define CFM 128
#define BN 2
#define HWFM (HFM*WFM)          // 8192
#define NPIX (BN*HWFM)          // 16384
#define KQ 6000
#define KQPAD 6016
#define NNEG 60
#define NE (NPIX*NNEG)          // 983040
#define EHALF_U 491520u
#define MSHIFT 15.0f

typedef _Float16 f16_8 __attribute__((ext_vector_type(8)));
typedef float f32_4 __attribute__((ext_vector_type(4)));

// ---------------- JAX threefry2x32 (bit-exact) ----------------
__host__ __device__ __forceinline__ void threefry2x32(uint32_t k0, uint32_t k1,
                                                      uint32_t x0, uint32_t x1,
                                                      uint32_t* o0, uint32_t* o1) {
  uint32_t ks2 = k0 ^ k1 ^ 0x1BD11BDAu;
  x0 += k0; x1 += k1;
#define TFR(r) { x0 += x1; x1 = (x1 << (r)) | (x1 >> (32 - (r))); x1 ^= x0; }
  TFR(13) TFR(15) TFR(26) TFR(6)
  x0 += k1;  x1 += ks2 + 1u;
  TFR(17) TFR(29) TFR(16) TFR(24)
  x0 += ks2; x1 += k0 + 2u;
  TFR(13) TFR(15) TFR(26) TFR(6)
  x0 += k0;  x1 += k1 + 3u;
  TFR(17) TFR(29) TFR(16) TFR(24)
  x0 += k1;  x1 += ks2 + 4u;
  TFR(13) TFR(15) TFR(26) TFR(6)
  x0 += ks2; x1 += k0 + 5u;
#undef TFR
  *o0 = x0; *o1 = x1;
}

// grid_sample coordinate helper (reference op order)
__device__ __forceinline__ void gs_coord(float t, float halfdim, float maxc,
                                         int* i0, int* i1, float* w) {
  float g = 2.0f * t - 1.0f;
  float x = (g + 1.0f) * halfdim - 0.5f;
  x = fminf(fmaxf(x, 0.0f), maxc);
  float f = floorf(x);
  *i0 = (int)f;
  *w = x - f;
  *i1 = (int)fminf(f + 1.0f, maxc);
}

__global__ void k_initS(float* __restrict__ S, int* __restrict__ count) {
  int i = blockIdx.x * 256 + threadIdx.x;
  if (i < NPIX) S[i] = 0.0f;
  if (i == 0) *count = 0;
}

// ref [b,c,hw] -> QT fp32 [b,hw,c];  tgt [b,c,hw] -> tgtTf16 [b,hw,c] f16
__global__ void k_transpose(const float* __restrict__ ref, const float* __restrict__ tgt,
                            float* __restrict__ QT, _Float16* __restrict__ tgtTf16) {
  __shared__ float tile[32][33];
  int z = blockIdx.z;
  int arr = z >> 1, b = z & 1;
  const float* src = (arr == 0 ? ref : tgt) + (size_t)b * CFM * HWFM;
  int x0 = blockIdx.x * 32;   // hw
  int y0 = blockIdx.y * 32;   // c
  int tx = threadIdx.x, ty = threadIdx.y;
#pragma unroll
  for (int i = 0; i < 32; i += 8)
    tile[ty + i][tx] = src[(size_t)(y0 + ty + i) * HWFM + x0 + tx];
  __syncthreads();
  if (arr == 0) {
    float* dst = QT + (size_t)b * HWFM * CFM;
#pragma unroll
    for (int i = 0; i < 32; i += 8)
      dst[(size_t)(x0 + ty + i) * CFM + (y0 + tx)] = tile[tx][ty + i];
  } else {
    _Float16* dst = tgtTf16 + (size_t)b * HWFM * CFM;
#pragma unroll
    for (int i = 0; i < 32; i += 8)
      dst[(size_t)(x0 + ty + i) * CFM + (y0 + tx)] = (_Float16)tile[tx][ty + i];
  }
}

// transpose queue [128][6000] fp32 -> [6016][128] f16 (rows 6000..6015 zero)
__global__ void k_qtrans(const float* __restrict__ queue, _Float16* __restrict__ queueTf) {
  __shared__ float tile[32][33];
  int n0 = blockIdx.x * 32;   // queue col
  int c0 = blockIdx.y * 32;   // channel
  int tx = threadIdx.x, ty = threadIdx.y;
#pragma unroll
  for (int i = 0; i < 32; i += 8) {
    int n = n0 + tx;
    tile[ty + i][tx] = (n < KQ) ? queue[(size_t)(c0 + ty + i) * KQ + n] : 0.0f;
  }
  __syncthreads();
#pragma unroll
  for (int i = 0; i < 32; i += 8)
    queueTf[(size_t)(n0 + ty + i) * CFM + (c0 + tx)] = (_Float16)tile[tx][ty + i];
}

// normalize each row of QT (length 128) in place + emit f16 copy
__global__ void k_normq(float* __restrict__ QT, _Float16* __restrict__ QTf) {
  int p = blockIdx.x, c = threadIdx.x;
  float v = QT[p * CFM + c];
  float ss = v * v;
#pragma unroll
  for (int off = 32; off; off >>= 1) ss += __shfl_down(ss, off, 64);
  __shared__ float s2[2];
  if ((c & 63) == 0) s2[c >> 6] = ss;
  __syncthreads();
  float inv = 1.0f / fmaxf(sqrtf(s2[0] + s2[1]), 1e-12f);
  float nv = v * inv;
  QT[p * CFM + c] = nv;
  QTf[p * CFM + c] = (_Float16)nv;
}

__global__ void k_qnorms(const float* __restrict__ queue, float* __restrict__ qInv) {
  int k = blockIdx.x * 256 + threadIdx.x;
  if (k >= KQ) return;
  float ss = 0.0f;
  for (int c = 0; c < CFM; c++) { float v = queue[c * KQ + k]; ss += v * v; }
  qInv[k] = 1.0f / fmaxf(sqrtf(ss), 1e-12f);
}

// per pixel: mask, l_pos, x_right, and compaction of unmasked pixel ids.
__global__ void k_prelude(const float* __restrict__ target_l, const float* __restrict__ target_r,
                          const float* __restrict__ QT, const _Float16* __restrict__ tgtTf,
                          float* __restrict__ S, float* __restrict__ logit0,
                          float* __restrict__ maskArr, float* __restrict__ xr,
                          int* __restrict__ count, int* __restrict__ list) {
  int p = blockIdx.x;
  int c = threadIdx.x;
  int b = p >> 13;
  int rem = p & (HWFM - 1);
  int i = rem >> 7, j = rem & 127;
  const float stepx = 1.0f / 127.0f, stepy = 1.0f / 63.0f;
  float xb = (j == 127) ? 1.0f : j * stepx;
  float yb = (i == 63) ? 1.0f : i * stepy;
  const float* tl = target_l + (size_t)b * 256 * 512;
  const float* tr = target_r + (size_t)b * 256 * 512;
  float dl = tl[(4 * i) * 512 + 4 * j] * 0.25f;

  int y0i, y1i; float wy;
  gs_coord(yb, 32.0f, 63.0f, &y0i, &y1i, &wy);
  float t = xb - dl * (1.0f / 128.0f);
  int x0i, x1i; float wx;
  gs_coord(t, 64.0f, 127.0f, &x0i, &x1i, &wx);

  auto innerv = [&](int y, int x) -> float {
    float xbx = (x == 127) ? 1.0f : x * stepx;
    float drv = tr[(4 * y) * 512 + 4 * x] * 0.25f;
    float ti = xbx + drv * (1.0f / 128.0f);
    float g = 2.0f * ti - 1.0f;
    float ix2 = fminf(fmaxf((g + 1.0f) * 64.0f - 0.5f, 0.0f), 127.0f);
    float x0f = floorf(ix2);
    float wxp = ix2 - x0f;
    float x1f = fminf(x0f + 1.0f, 127.0f);
    return x0f * (1.0f - wxp) + x1f * wxp;
  };
  float v00 = innerv(y0i, x0i), v01 = innerv(y0i, x1i);
  float v10 = innerv(y1i, x0i), v11 = innerv(y1i, x1i);
  float l2r2l = v00 * (1.0f - wx) * (1.0f - wy) + v01 * wx * (1.0f - wy)
              + v10 * (1.0f - wx) * wy + v11 * wx * wy;
  bool masko = fabsf((float)j - l2r2l) < 3.0f;
  float mk = (masko && (dl > 0.0f) && (t >= 0.0f)) ? 1.0f : 0.0f;

  float w00 = (1.0f - wx) * (1.0f - wy), w01 = wx * (1.0f - wy);
  float w10 = (1.0f - wx) * wy,          w11 = wx * wy;
  int bo = b * HWFM;
  const _Float16* r00 = tgtTf + (size_t)(bo + y0i * WFM + x0i) * CFM;
  const _Float16* r01 = tgtTf + (size_t)(bo + y0i * WFM + x1i) * CFM;
  const _Float16* r10 = tgtTf + (size_t)(bo + y1i * WFM + x0i) * CFM;
  const _Float16* r11 = tgtTf + (size_t)(bo + y1i * WFM + x1i) * CFM;
  float q = QT[(size_t)p * CFM + c];
  float v = w00 * (float)r00[c] + w01 * (float)r01[c]
          + w10 * (float)r10[c] + w11 * (float)r11[c];
  float dot = q * v, ss = v * v;
#pragma unroll
  for (int off = 32; off; off >>= 1) {
    dot += __shfl_down(dot, off, 64);
    ss  += __shfl_down(ss,  off, 64);
  }
  __shared__ float rd[2], rs[2];
  if ((c & 63) == 0) { rd[c >> 6] = dot; rs[c >> 6] = ss; }
  __syncthreads();
  if (c == 0) {
    float dt = rd[0] + rd[1], st = rs[0] + rs[1];
    float lpos = dt / fmaxf(sqrtf(st), 1e-12f);
    float lg0 = (lpos * mk) / 0.07f;
    logit0[p] = lg0;
    maskArr[p] = mk;
    xr[p] = t * 128.0f;
    atomicAdd(&S[p], expf(lg0 - MSHIFT));
    if (mk > 0.0f) {
      int idx = atomicAdd(count, 1);
      list[idx] = p;
    }
  }
}

// -------- negatives: wave-per-(compacted)pixel, MFMA reduction --------
__global__ __launch_bounds__(256) void k_negatives_mfma(
    const _Float16* __restrict__ QTf, const _Float16* __restrict__ tgtTf,
    const float* __restrict__ xr, float* __restrict__ S,
    const int* __restrict__ count, const int* __restrict__ list,
    uint32_t k1a, uint32_t k1b, uint32_t k2a, uint32_t k2b) {
  int tid = threadIdx.x;
  int wave = tid >> 6;
  int lane = tid & 63;
  int quad = lane >> 4;
  int l16 = lane & 15;
  int cnt = *count;
  int slot = blockIdx.x * 4 + wave;
  if (slot >= cnt) return;
  int p = list[slot];
  int b = p >> 13;

  // ---- Phase A: per-lane RNG for negative n = lane ----
  uint32_t e = (uint32_t)(p * NNEG + lane);
  uint32_t h0, h1;
  threefry2x32(k1a, k1b, e, e + (uint32_t)NE, &h0, &h1);
  uint32_t off = ((h0 % 24u) * 16u + (h1 % 24u)) % 24u;
  float mag = (float)(1u + off);
  uint32_t ub;
  {
    uint32_t a, bm;
    if (e < EHALF_U) { threefry2x32(k2a, k2b, e, e + EHALF_U, &a, &bm); ub = a; }
    else             { threefry2x32(k2a, k2b, e - EHALF_U, e, &a, &bm); ub = bm; }
  }
  float u = __uint_as_float((ub >> 9) | 0x3F800000u) - 1.0f;
  float sg = (u > 0.5f) ? 1.0f : ((u < 0.5f) ? -1.0f : 0.0f);

  float xrp = xr[p];
  float v = xrp + mag * sg;
  float r = fmodf(v, 128.0f);
  if (r < 0.0f) r += 128.0f;
  float fx = r * (1.0f / 128.0f);
  float fy = fx * (1.0f / 64.0f);
  int x0i, x1i, y0i, y1i; float wx, wy;
  gs_coord(fx, 64.0f, 127.0f, &x0i, &x1i, &wx);
  gs_coord(fy, 32.0f, 63.0f, &y0i, &y1i, &wy);   // y0=0, y1=1 always here
  float w00 = (1.0f - wx) * (1.0f - wy), w01 = wx * (1.0f - wy);
  float w10 = (1.0f - wx) * wy,          w11 = wx * wy;

  // ---- Phase B ---- (compacted => mask == 1)
  const float mask_p = 1.0f / 0.07f;
  const _Float16* qrow = QTf + (size_t)p * CFM;
  f16_8 Qf[4];
#pragma unroll
  for (int s = 0; s < 4; s++)
    Qf[s] = *(const f16_8*)(qrow + s * 32 + quad * 8);

  const _Float16* tb0 = tgtTf + (size_t)(b * HWFM) * CFM;        // y=0 rows
  const _Float16* tb1 = tgtTf + (size_t)(b * HWFM + WFM) * CFM;  // y=1 rows
  float esum = 0.0f;

#pragma unroll
  for (int g = 0; g < 4; g++) {
    int srcl = g * 16 + l16;
    float gw00 = __shfl(w00, srcl, 64);
    float gw01 = __shfl(w01, srcl, 64);
    float gw10 = __shfl(w10, srcl, 64);
    float gw11 = __shfl(w11, srcl, 64);
    int gx0 = __shfl(x0i, srcl, 64);
    int gx1 = __shfl(x1i, srcl, 64);
    const _Float16* r00 = tb0 + (size_t)gx0 * CFM;
    const _Float16* r01 = tb0 + (size_t)gx1 * CFM;
    const _Float16* r10 = tb1 + (size_t)gx0 * CFM;
    const _Float16* r11 = tb1 + (size_t)gx1 * CFM;

    f32_4 accD = (f32_4){0.0f, 0.0f, 0.0f, 0.0f};
    f32_4 accS = (f32_4){0.0f, 0.0f, 0.0f, 0.0f};
#pragma unroll
    for (int s = 0; s < 4; s++) {
      int ch = s * 32 + quad * 8;
      f16_8 a8 = *(const f16_8*)(r00 + ch);
      f16_8 b8 = *(const f16_8*)(r01 + ch);
      f16_8 c8 = *(const f16_8*)(r10 + ch);
      f16_8 d8 = *(const f16_8*)(r11 + ch);
      f16_8 vf;
#pragma unroll
      for (int jj = 0; jj < 8; jj++) {
        float vv = gw00 * (float)a8[jj] + gw01 * (float)b8[jj]
                 + gw10 * (float)c8[jj] + gw11 * (float)d8[jj];
        vf[jj] = (_Float16)vv;
      }
      accD = __builtin_amdgcn_mfma_f32_16x16x32_f16(vf, Qf[s], accD, 0, 0, 0);
      accS = __builtin_amdgcn_mfma_f32_16x16x32_f16(vf, vf, accS, 0, 0, 0);
    }
    // diagonal lanes: row (quad*4+reg) == col l16
    if ((l16 >> 2) == quad) {
      int rg = l16 & 3;
      int n_g = g * 16 + l16;
      if (n_g < NNEG) {
        float dot = accD[rg], ssn = accS[rg];
        float ln = dot / fmaxf(sqrtf(ssn), 1e-12f);
        float lg = ln * mask_p;
        esum += __expf(lg - MSHIFT);
      }
    }
  }
#pragma unroll
  for (int o = 32; o; o >>= 1) esum += __shfl_xor(esum, o, 64);
  if (lane == 0) atomicAdd(&S[p], esum);
}

// -------- MFMA l_q GEMM over compacted rows, fused with exp-sum --------
__global__ __launch_bounds__(256) void k_gemm_mfma(
    const _Float16* __restrict__ QTf,     // [NPIX][128]
    const _Float16* __restrict__ queueTf, // [6016][128]
    const float* __restrict__ qInv,
    float* __restrict__ S,
    const int* __restrict__ count, const int* __restrict__ list) {
  __shared__ float Srow[64];
  int tid = threadIdx.x;
  int cnt = *count;
  if ((int)(blockIdx.y * 64) >= cnt) return;   // block-uniform early exit
  int wave = tid >> 6;
  int lane = tid & 63;
  int quad = lane >> 4;
  int l16 = lane & 15;
  int wm = wave >> 1;
  int wn = wave & 1;
  int p0 = blockIdx.y * 64 + wm * 32;
  int n0 = blockIdx.x * 128 + wn * 64;

  if (tid < 64) Srow[tid] = 0.0f;

  // indirect A rows
  int prow[2];
#pragma unroll
  for (int mt = 0; mt < 2; mt++)
    prow[mt] = list[min(p0 + mt * 16 + l16, cnt - 1)];

  f16_8 Af[2][4];
#pragma unroll
  for (int mt = 0; mt < 2; mt++) {
    const _Float16* arow = QTf + (size_t)prow[mt] * CFM + quad * 8;
#pragma unroll
    for (int ks = 0; ks < 4; ks++)
      Af[mt][ks] = *(const f16_8*)(arow + ks * 32);
  }

  f16_8 Bf[4][4];
  const _Float16* brow = queueTf + (size_t)(n0 + l16) * CFM + quad * 8;
#pragma unroll
  for (int nt = 0; nt < 4; nt++)
#pragma unroll
    for (int ks = 0; ks < 4; ks++)
      Bf[nt][ks] = *(const f16_8*)(brow + (size_t)nt * 16 * CFM + ks * 32);

  f32_4 acc[2][4];
#pragma unroll
  for (int mt = 0; mt < 2; mt++)
#pragma unroll
    for (int nt = 0; nt < 4; nt++)
      acc[mt][nt] = (f32_4){0.0f, 0.0f, 0.0f, 0.0f};

#pragma unroll
  for (int ks = 0; ks < 4; ks++)
#pragma unroll
    for (int mt = 0; mt < 2; mt++)
#pragma unroll
      for (int nt = 0; nt < 4; nt++)
        acc[mt][nt] = __builtin_amdgcn_mfma_f32_16x16x32_f16(Af[mt][ks], Bf[nt][ks], acc[mt][nt], 0, 0, 0);

  // compacted => mask = 1 for valid rows; 0 weight for pad rows
  float mrow[2][4];
#pragma unroll
  for (int mt = 0; mt < 2; mt++)
#pragma unroll
    for (int r = 0; r < 4; r++)
      mrow[mt][r] = (p0 + mt * 16 + quad * 4 + r < cnt) ? (1.0f / 0.07f) : 0.0f;

  float rowsum[2][4] = {{0.0f,0.0f,0.0f,0.0f},{0.0f,0.0f,0.0f,0.0f}};
#pragma unroll
  for (int nt = 0; nt < 4; nt++) {
    int n = n0 + nt * 16 + l16;
    bool valid = n < KQ;
    float qi = valid ? qInv[n] : 0.0f;
#pragma unroll
    for (int mt = 0; mt < 2; mt++)
#pragma unroll
      for (int r = 0; r < 4; r++) {
        float lg = acc[mt][nt][r] * qi * mrow[mt][r];
        float ev = valid ? __expf(lg - MSHIFT) : 0.0f;
        rowsum[mt][r] += ev;
      }
  }
#pragma unroll
  for (int mt = 0; mt < 2; mt++)
#pragma unroll
    for (int r = 0; r < 4; r++) {
      float vv = rowsum[mt][r];
      vv += __shfl_xor(vv, 1);
      vv += __shfl_xor(vv, 2);
      vv += __shfl_xor(vv, 4);
      vv += __shfl_xor(vv, 8);
      rowsum[mt][r] = vv;
    }
  __syncthreads();
  if (l16 == 0) {
#pragma unroll
    for (int mt = 0; mt < 2; mt++)
#pragma unroll
      for (int r = 0; r < 4; r++)
        atomicAdd(&Srow[wm * 32 + mt * 16 + quad * 4 + r], rowsum[mt][r]);
  }
  __syncthreads();
  if (tid < 64) {
    int pr = blockIdx.y * 64 + tid;
    if (pr < cnt) atomicAdd(&S[list[pr]], Srow[tid]);
  }
}

__global__ void k_finalize(const float* __restrict__ S, const float* __restrict__ logit0,
                           const float* __restrict__ maskArr, float* __restrict__ out) {
  int tid = threadIdx.x;
  const float cmask = logf(6061.0f);   // masked row: all 6061 logits are exactly 0
  double acc = 0.0;
  for (int p = tid; p < NPIX; p += 256) {
    float term = (maskArr[p] > 0.0f) ? (logf(S[p]) + MSHIFT - logit0[p]) : cmask;
    acc += (double)term;
  }
#pragma unroll
  for (int off = 32; off; off >>= 1) acc += __shfl_down(acc, off, 64);
  __shared__ double sd[4];
  if ((tid & 63) == 0) sd[tid >> 6] = acc;
  __syncthreads();
  if (tid == 0) out[0] = (float)((sd[0] + sd[1] + sd[2] + sd[3]) / (double)NPIX);
}

extern "C" void kernel_launch(void* const* d_in, const int* in_sizes, int n_in,
                              void* d_out, int out_size, void* d_ws, size_t ws_size,
                              hipStream_t stream) {
  const float* ref   = (const float*)d_in[0];
  const float* tgt   = (const float*)d_in[1];
  const float* tl    = (const float*)d_in[2];
  const float* tr    = (const float*)d_in[3];
  const float* queue = (const float*)d_in[4];
  float* out = (float*)d_out;
  float* ws = (float*)d_ws;

  float* QT   = ws;                          // [NPIX][128] fp32  (2097152)
  float* qInv = ws + 2097152;                // 6016
  float* S    = ws + 2103168;                // 16384
  float* lg0  = ws + 2119552;                // 16384
  float* mk   = ws + 2135936;                // 16384
  float* xr   = ws + 2152320;                // 16384 -> ends 2168704
  _Float16* QTf     = (_Float16*)(ws + 2168704);   // NPIX*128 f16  (1048576 fl)
  _Float16* queueTf = (_Float16*)(ws + 3217280);   // 6016*128 f16  (385024 fl)
  _Float16* tgtTf   = (_Float16*)(ws + 3602304);   // NPIX*128 f16  (1048576 fl)
  int* count = (int*)(ws + 4650880);               // 1
  int* list  = (int*)(ws + 4650896);               // NPIX ints

  // JAX: k1, k2 = split(key(1234))
  uint32_t b0o0, b0o1, b1o0, b1o1;
  threefry2x32(0u, 1234u, 0u, 2u, &b0o0, &b0o1);
  threefry2x32(0u, 1234u, 1u, 3u, &b1o0, &b1o1);
  uint32_t k1a = b0o0, k1b = b1o0, k2a = b0o1, k2b = b1o1;

  k_initS<<<dim3(NPIX / 256), dim3(256), 0, stream>>>(S, count);
  k_transpose<<<dim3(HWFM / 32, CFM / 32, 4), dim3(32, 8), 0, stream>>>(ref, tgt, QT, tgtTf);
  k_qtrans<<<dim3(KQPAD / 32, CFM / 32), dim3(32, 8), 0, stream>>>(queue, queueTf);
  k_normq<<<dim3(NPIX), dim3(128), 0, stream>>>(QT, QTf);
  k_qnorms<<<dim3((KQ + 255) / 256), dim3(256), 0, stream>>>(queue, qInv);
  k_prelude<<<dim3(NPIX), dim3(128), 0, stream>>>(tl, tr, QT, tgtTf, S, lg0, mk, xr, count, list);
  k_negatives_mfma<<<dim3(NPIX / 4), dim3(256), 0, stream>>>(QTf, tgtTf, xr, S, count, list, k1a, k1b, k2a, k2b);
  k_gemm_mfma<<<dim3(KQPAD / 128, NPIX / 64), dim3(256), 0, stream>>>(QTf, queueTf, qInv, S, count, list);
  k_finalize<<<dim3(1), dim3(256), 0, stream>>>(S, lg0, mk, out);
}

// Round 5
// 290.817 us; speedup vs baseline: 3.1979x; 1.0381x over previous
//
#include <hip/hip_runtime.h>
#include <stdint.h>
#include <math.h>

#define HFM 64
#define WFM 128
#define CFM 128
#define BN 2
#define HWFM (HFM*WFM)          // 8192
#define NPIX (BN*HWFM)          // 16384
#define KQ 6000
#define KQPAD 6016
#define NNEG 60
#define NE (NPIX*NNEG)          // 983040
#define EHALF_U 491520u
#define MSHIFT 15.0f

typedef _Float16 f16_8 __attribute__((ext_vector_type(8)));
typedef _Float16 f16_2 __attribute__((ext_vector_type(2)));
typedef float f32_4 __attribute__((ext_vector_type(4)));

// ---------------- JAX threefry2x32 (bit-exact) ----------------
__host__ __device__ __forceinline__ void threefry2x32(uint32_t k0, uint32_t k1,
                                                      uint32_t x0, uint32_t x1,
                                                      uint32_t* o0, uint32_t* o1) {
  uint32_t ks2 = k0 ^ k1 ^ 0x1BD11BDAu;
  x0 += k0; x1 += k1;
#define TFR(r) { x0 += x1; x1 = (x1 << (r)) | (x1 >> (32 - (r))); x1 ^= x0; }
  TFR(13) TFR(15) TFR(26) TFR(6)
  x0 += k1;  x1 += ks2 + 1u;
  TFR(17) TFR(29) TFR(16) TFR(24)
  x0 += ks2; x1 += k0 + 2u;
  TFR(13) TFR(15) TFR(26) TFR(6)
  x0 += k0;  x1 += k1 + 3u;
  TFR(17) TFR(29) TFR(16) TFR(24)
  x0 += k1;  x1 += ks2 + 4u;
  TFR(13) TFR(15) TFR(26) TFR(6)
  x0 += ks2; x1 += k0 + 5u;
#undef TFR
  *o0 = x0; *o1 = x1;
}

// grid_sample coordinate helper (reference op order)
__device__ __forceinline__ void gs_coord(float t, float halfdim, float maxc,
                                         int* i0, int* i1, float* w) {
  float g = 2.0f * t - 1.0f;
  float x = (g + 1.0f) * halfdim - 0.5f;
  x = fminf(fmaxf(x, 0.0f), maxc);
  float f = floorf(x);
  *i0 = (int)f;
  *w = x - f;
  *i1 = (int)fminf(f + 1.0f, maxc);
}

// ref [b,c,hw] -> refTf f16 [b,hw,c];  tgt [b,c,hw] -> tgtTf f16 [b,hw,c]
__global__ void k_transpose(const float* __restrict__ ref, const float* __restrict__ tgt,
                            _Float16* __restrict__ refTf, _Float16* __restrict__ tgtTf) {
  __shared__ float tile[32][33];
  int z = blockIdx.z;
  int arr = z >> 1, b = z & 1;
  const float* src = (arr == 0 ? ref : tgt) + (size_t)b * CFM * HWFM;
  _Float16* dst = (arr == 0 ? refTf : tgtTf) + (size_t)b * HWFM * CFM;
  int x0 = blockIdx.x * 32;   // hw
  int y0 = blockIdx.y * 32;   // c
  int tx = threadIdx.x, ty = threadIdx.y;
#pragma unroll
  for (int i = 0; i < 32; i += 8)
    tile[ty + i][tx] = src[(size_t)(y0 + ty + i) * HWFM + x0 + tx];
  __syncthreads();
#pragma unroll
  for (int i = 0; i < 32; i += 8)
    dst[(size_t)(x0 + ty + i) * CFM + (y0 + tx)] = (_Float16)tile[tx][ty + i];
}

// transpose queue [128][6000] fp32 -> [6016][128] f16 (rows 6000..6015 zero)
__global__ void k_qtrans(const float* __restrict__ queue, _Float16* __restrict__ queueTf) {
  __shared__ float tile[32][33];
  int n0 = blockIdx.x * 32;   // queue col
  int c0 = blockIdx.y * 32;   // channel
  int tx = threadIdx.x, ty = threadIdx.y;
#pragma unroll
  for (int i = 0; i < 32; i += 8) {
    int n = n0 + tx;
    tile[ty + i][tx] = (n < KQ) ? queue[(size_t)(c0 + ty + i) * KQ + n] : 0.0f;
  }
  __syncthreads();
#pragma unroll
  for (int i = 0; i < 32; i += 8)
    queueTf[(size_t)(n0 + ty + i) * CFM + (c0 + tx)] = (_Float16)tile[tx][ty + i];
}

// queue column inv-norms + reset compaction counter
__global__ void k_qnorms_init(const float* __restrict__ queue, float* __restrict__ qInv,
                              int* __restrict__ count) {
  int k = blockIdx.x * 256 + threadIdx.x;
  if (k == 0) *count = 0;
  if (k >= KQ) return;
  float ss = 0.0f;
  for (int c = 0; c < CFM; c++) { float v = queue[c * KQ + k]; ss += v * v; }
  qInv[k] = 1.0f / fmaxf(sqrtf(ss), 1e-12f);
}

// per pixel (wave-per-pixel, 4 pixels/block): mask; if unmasked: fused query
// normalize (writes QTf), positive dot, l_pos, xr, S store, list append.
__global__ __launch_bounds__(256) void k_prelude(
    const float* __restrict__ target_l, const float* __restrict__ target_r,
    const _Float16* __restrict__ refTf, const _Float16* __restrict__ tgtTf,
    _Float16* __restrict__ QTf,
    float* __restrict__ S, float* __restrict__ logit0,
    float* __restrict__ maskArr, float* __restrict__ xr,
    int* __restrict__ count, int* __restrict__ list) {
  int tid = threadIdx.x;
  int wave = tid >> 6, lane = tid & 63;
  int p = blockIdx.x * 4 + wave;
  int b = p >> 13;
  int rem = p & (HWFM - 1);
  int i = rem >> 7, j = rem & 127;
  const float stepx = 1.0f / 127.0f, stepy = 1.0f / 63.0f;
  float xb = (j == 127) ? 1.0f : j * stepx;
  float yb = (i == 63) ? 1.0f : i * stepy;
  const float* tl = target_l + (size_t)b * 256 * 512;
  const float* tr = target_r + (size_t)b * 256 * 512;
  float dl = tl[(4 * i) * 512 + 4 * j] * 0.25f;   // broadcast load

  int y0i, y1i; float wy;
  gs_coord(yb, 32.0f, 63.0f, &y0i, &y1i, &wy);
  float t = xb - dl * (1.0f / 128.0f);
  int x0i, x1i; float wx;
  gs_coord(t, 64.0f, 127.0f, &x0i, &x1i, &wx);

  auto innerv = [&](int y, int x) -> float {
    float xbx = (x == 127) ? 1.0f : x * stepx;
    float drv = tr[(4 * y) * 512 + 4 * x] * 0.25f;  // broadcast load
    float ti = xbx + drv * (1.0f / 128.0f);
    float g = 2.0f * ti - 1.0f;
    float ix2 = fminf(fmaxf((g + 1.0f) * 64.0f - 0.5f, 0.0f), 127.0f);
    float x0f = floorf(ix2);
    float wxp = ix2 - x0f;
    float x1f = fminf(x0f + 1.0f, 127.0f);
    return x0f * (1.0f - wxp) + x1f * wxp;
  };
  float v00 = innerv(y0i, x0i), v01 = innerv(y0i, x1i);
  float v10 = innerv(y1i, x0i), v11 = innerv(y1i, x1i);
  float l2r2l = v00 * (1.0f - wx) * (1.0f - wy) + v01 * wx * (1.0f - wy)
              + v10 * (1.0f - wx) * wy + v11 * wx * wy;
  bool masko = fabsf((float)j - l2r2l) < 3.0f;
  bool mk = masko && (dl > 0.0f) && (t >= 0.0f);
  if (lane == 0) maskArr[p] = mk ? 1.0f : 0.0f;
  if (!mk) return;   // wave-uniform: masked pixels need nothing else

  // ---- fused query normalize (lane = 2 channels) ----
  int c2 = lane * 2;
  f16_2 q2 = *(const f16_2*)(refTf + (size_t)p * CFM + c2);
  float q0 = (float)q2[0], q1 = (float)q2[1];
  float ssq = q0 * q0 + q1 * q1;
#pragma unroll
  for (int o = 32; o; o >>= 1) ssq += __shfl_xor(ssq, o, 64);
  float inv = 1.0f / fmaxf(sqrtf(ssq), 1e-12f);
  float qn0 = q0 * inv, qn1 = q1 * inv;
  f16_2 qw; qw[0] = (_Float16)qn0; qw[1] = (_Float16)qn1;
  *(f16_2*)(QTf + (size_t)p * CFM + c2) = qw;

  // ---- positive bilinear sample + dot ----
  float w00 = (1.0f - wx) * (1.0f - wy), w01 = wx * (1.0f - wy);
  float w10 = (1.0f - wx) * wy,          w11 = wx * wy;
  int bo = b * HWFM;
  f16_2 a2 = *(const f16_2*)(tgtTf + (size_t)(bo + y0i * WFM + x0i) * CFM + c2);
  f16_2 b2 = *(const f16_2*)(tgtTf + (size_t)(bo + y0i * WFM + x1i) * CFM + c2);
  f16_2 cc2 = *(const f16_2*)(tgtTf + (size_t)(bo + y1i * WFM + x0i) * CFM + c2);
  f16_2 d2 = *(const f16_2*)(tgtTf + (size_t)(bo + y1i * WFM + x1i) * CFM + c2);
  float v0 = w00 * (float)a2[0] + w01 * (float)b2[0] + w10 * (float)cc2[0] + w11 * (float)d2[0];
  float v1 = w00 * (float)a2[1] + w01 * (float)b2[1] + w10 * (float)cc2[1] + w11 * (float)d2[1];
  float dot = qn0 * v0 + qn1 * v1;
  float ssv = v0 * v0 + v1 * v1;
#pragma unroll
  for (int o = 32; o; o >>= 1) {
    dot += __shfl_xor(dot, o, 64);
    ssv += __shfl_xor(ssv, o, 64);
  }
  if (lane == 0) {
    float lpos = dot / fmaxf(sqrtf(ssv), 1e-12f);
    float lg0 = lpos / 0.07f;
    logit0[p] = lg0;
    xr[p] = t * 128.0f;
    S[p] = expf(lg0 - MSHIFT);   // first writer; later kernels atomicAdd
    int idx = atomicAdd(count, 1);
    list[idx] = p;
  }
}

// -------- negatives: wave-per-(compacted)pixel, MFMA reduction --------
__global__ __launch_bounds__(256) void k_negatives_mfma(
    const _Float16* __restrict__ QTf, const _Float16* __restrict__ tgtTf,
    const float* __restrict__ xr, float* __restrict__ S,
    const int* __restrict__ count, const int* __restrict__ list,
    uint32_t k1a, uint32_t k1b, uint32_t k2a, uint32_t k2b) {
  int tid = threadIdx.x;
  int wave = tid >> 6;
  int lane = tid & 63;
  int quad = lane >> 4;
  int l16 = lane & 15;
  int cnt = *count;
  int slot = blockIdx.x * 4 + wave;
  if (slot >= cnt) return;
  int p = list[slot];
  int b = p >> 13;

  // ---- Phase A: per-lane RNG for negative n = lane ----
  uint32_t e = (uint32_t)(p * NNEG + lane);
  uint32_t h0, h1;
  threefry2x32(k1a, k1b, e, e + (uint32_t)NE, &h0, &h1);
  uint32_t off = ((h0 % 24u) * 16u + (h1 % 24u)) % 24u;
  float mag = (float)(1u + off);
  uint32_t ub;
  {
    uint32_t a, bm;
    if (e < EHALF_U) { threefry2x32(k2a, k2b, e, e + EHALF_U, &a, &bm); ub = a; }
    else             { threefry2x32(k2a, k2b, e - EHALF_U, e, &a, &bm); ub = bm; }
  }
  float u = __uint_as_float((ub >> 9) | 0x3F800000u) - 1.0f;
  float sg = (u > 0.5f) ? 1.0f : ((u < 0.5f) ? -1.0f : 0.0f);

  float xrp = xr[p];
  float v = xrp + mag * sg;
  float r = fmodf(v, 128.0f);
  if (r < 0.0f) r += 128.0f;
  float fx = r * (1.0f / 128.0f);
  float fy = fx * (1.0f / 64.0f);
  int x0i, x1i, y0i, y1i; float wx, wy;
  gs_coord(fx, 64.0f, 127.0f, &x0i, &x1i, &wx);
  gs_coord(fy, 32.0f, 63.0f, &y0i, &y1i, &wy);   // y0=0, y1=1 always here
  float w00 = (1.0f - wx) * (1.0f - wy), w01 = wx * (1.0f - wy);
  float w10 = (1.0f - wx) * wy,          w11 = wx * wy;

  // ---- Phase B ---- (compacted => mask == 1)
  const float mask_p = 1.0f / 0.07f;
  const _Float16* qrow = QTf + (size_t)p * CFM;
  f16_8 Qf[4];
#pragma unroll
  for (int s = 0; s < 4; s++)
    Qf[s] = *(const f16_8*)(qrow + s * 32 + quad * 8);

  const _Float16* tb0 = tgtTf + (size_t)(b * HWFM) * CFM;        // y=0 rows
  const _Float16* tb1 = tgtTf + (size_t)(b * HWFM + WFM) * CFM;  // y=1 rows
  float esum = 0.0f;

#pragma unroll
  for (int g = 0; g < 4; g++) {
    int srcl = g * 16 + l16;
    float gw00 = __shfl(w00, srcl, 64);
    float gw01 = __shfl(w01, srcl, 64);
    float gw10 = __shfl(w10, srcl, 64);
    float gw11 = __shfl(w11, srcl, 64);
    int gx0 = __shfl(x0i, srcl, 64);
    int gx1 = __shfl(x1i, srcl, 64);
    const _Float16* r00 = tb0 + (size_t)gx0 * CFM;
    const _Float16* r01 = tb0 + (size_t)gx1 * CFM;
    const _Float16* r10 = tb1 + (size_t)gx0 * CFM;
    const _Float16* r11 = tb1 + (size_t)gx1 * CFM;

    f32_4 accD = (f32_4){0.0f, 0.0f, 0.0f, 0.0f};
    f32_4 accS = (f32_4){0.0f, 0.0f, 0.0f, 0.0f};
#pragma unroll
    for (int s = 0; s < 4; s++) {
      int ch = s * 32 + quad * 8;
      f16_8 a8 = *(const f16_8*)(r00 + ch);
      f16_8 b8 = *(const f16_8*)(r01 + ch);
      f16_8 c8 = *(const f16_8*)(r10 + ch);
      f16_8 d8 = *(const f16_8*)(r11 + ch);
      f16_8 vf;
#pragma unroll
      for (int jj = 0; jj < 8; jj++) {
        float vv = gw00 * (float)a8[jj] + gw01 * (float)b8[jj]
                 + gw10 * (float)c8[jj] + gw11 * (float)d8[jj];
        vf[jj] = (_Float16)vv;
      }
      accD = __builtin_amdgcn_mfma_f32_16x16x32_f16(vf, Qf[s], accD, 0, 0, 0);
      accS = __builtin_amdgcn_mfma_f32_16x16x32_f16(vf, vf, accS, 0, 0, 0);
    }
    // diagonal lanes: row (quad*4+reg) == col l16
    if ((l16 >> 2) == quad) {
      int rg = l16 & 3;
      int n_g = g * 16 + l16;
      if (n_g < NNEG) {
        float dot = accD[rg], ssn = accS[rg];
        float ln = dot / fmaxf(sqrtf(ssn), 1e-12f);
        float lg = ln * mask_p;
        esum += __expf(lg - MSHIFT);
      }
    }
  }
#pragma unroll
  for (int o = 32; o; o >>= 1) esum += __shfl_xor(esum, o, 64);
  if (lane == 0) atomicAdd(&S[p], esum);
}

// -------- MFMA l_q GEMM over compacted rows, fused with exp-sum --------
__global__ __launch_bounds__(256) void k_gemm_mfma(
    const _Float16* __restrict__ QTf,     // [NPIX][128]
    const _Float16* __restrict__ queueTf, // [6016][128]
    const float* __restrict__ qInv,
    float* __restrict__ S,
    const int* __restrict__ count, const int* __restrict__ list) {
  __shared__ float Srow[64];
  int tid = threadIdx.x;
  int cnt = *count;
  if ((int)(blockIdx.y * 64) >= cnt) return;   // block-uniform early exit
  int wave = tid >> 6;
  int lane = tid & 63;
  int quad = lane >> 4;
  int l16 = lane & 15;
  int wm = wave >> 1;
  int wn = wave & 1;
  int p0 = blockIdx.y * 64 + wm * 32;
  int n0 = blockIdx.x * 128 + wn * 64;

  if (tid < 64) Srow[tid] = 0.0f;

  // indirect A rows
  int prow[2];
#pragma unroll
  for (int mt = 0; mt < 2; mt++)
    prow[mt] = list[min(p0 + mt * 16 + l16, cnt - 1)];

  f16_8 Af[2][4];
#pragma unroll
  for (int mt = 0; mt < 2; mt++) {
    const _Float16* arow = QTf + (size_t)prow[mt] * CFM + quad * 8;
#pragma unroll
    for (int ks = 0; ks < 4; ks++)
      Af[mt][ks] = *(const f16_8*)(arow + ks * 32);
  }

  f16_8 Bf[4][4];
  const _Float16* brow = queueTf + (size_t)(n0 + l16) * CFM + quad * 8;
#pragma unroll
  for (int nt = 0; nt < 4; nt++)
#pragma unroll
    for (int ks = 0; ks < 4; ks++)
      Bf[nt][ks] = *(const f16_8*)(brow + (size_t)nt * 16 * CFM + ks * 32);

  f32_4 acc[2][4];
#pragma unroll
  for (int mt = 0; mt < 2; mt++)
#pragma unroll
    for (int nt = 0; nt < 4; nt++)
      acc[mt][nt] = (f32_4){0.0f, 0.0f, 0.0f, 0.0f};

#pragma unroll
  for (int ks = 0; ks < 4; ks++)
#pragma unroll
    for (int mt = 0; mt < 2; mt++)
#pragma unroll
      for (int nt = 0; nt < 4; nt++)
        acc[mt][nt] = __builtin_amdgcn_mfma_f32_16x16x32_f16(Af[mt][ks], Bf[nt][ks], acc[mt][nt], 0, 0, 0);

  // compacted => mask = 1 for valid rows; 0 weight for pad rows
  float mrow[2][4];
#pragma unroll
  for (int mt = 0; mt < 2; mt++)
#pragma unroll
    for (int r = 0; r < 4; r++)
      mrow[mt][r] = (p0 + mt * 16 + quad * 4 + r < cnt) ? (1.0f / 0.07f) : 0.0f;

  float rowsum[2][4] = {{0.0f,0.0f,0.0f,0.0f},{0.0f,0.0f,0.0f,0.0f}};
#pragma unroll
  for (int nt = 0; nt < 4; nt++) {
    int n = n0 + nt * 16 + l16;
    bool valid = n < KQ;
    float qi = valid ? qInv[n] : 0.0f;
#pragma unroll
    for (int mt = 0; mt < 2; mt++)
#pragma unroll
      for (int r = 0; r < 4; r++) {
        float lg = acc[mt][nt][r] * qi * mrow[mt][r];
        float ev = valid ? __expf(lg - MSHIFT) : 0.0f;
        rowsum[mt][r] += ev;
      }
  }
#pragma unroll
  for (int mt = 0; mt < 2; mt++)
#pragma unroll
    for (int r = 0; r < 4; r++) {
      float vv = rowsum[mt][r];
      vv += __shfl_xor(vv, 1);
      vv += __shfl_xor(vv, 2);
      vv += __shfl_xor(vv, 4);
      vv += __shfl_xor(vv, 8);
      rowsum[mt][r] = vv;
    }
  __syncthreads();
  if (l16 == 0) {
#pragma unroll
    for (int mt = 0; mt < 2; mt++)
#pragma unroll
      for (int r = 0; r < 4; r++)
        atomicAdd(&Srow[wm * 32 + mt * 16 + quad * 4 + r], rowsum[mt][r]);
  }
  __syncthreads();
  if (tid < 64) {
    int pr = blockIdx.y * 64 + tid;
    if (pr < cnt) atomicAdd(&S[list[pr]], Srow[tid]);
  }
}

__global__ void k_finalize(const float* __restrict__ S, const float* __restrict__ logit0,
                           const float* __restrict__ maskArr, float* __restrict__ out) {
  int tid = threadIdx.x;
  const float cmask = logf(6061.0f);   // masked row: all 6061 logits are exactly 0
  double acc = 0.0;
  for (int p = tid; p < NPIX; p += 256) {
    float term = (maskArr[p] > 0.0f) ? (logf(S[p]) + MSHIFT - logit0[p]) : cmask;
    acc += (double)term;
  }
#pragma unroll
  for (int off = 32; off; off >>= 1) acc += __shfl_down(acc, off, 64);
  __shared__ double sd[4];
  if ((tid & 63) == 0) sd[tid >> 6] = acc;
  __syncthreads();
  if (tid == 0) out[0] = (float)((sd[0] + sd[1] + sd[2] + sd[3]) / (double)NPIX);
}

extern "C" void kernel_launch(void* const* d_in, const int* in_sizes, int n_in,
                              void* d_out, int out_size, void* d_ws, size_t ws_size,
                              hipStream_t stream) {
  const float* ref   = (const float*)d_in[0];
  const float* tgt   = (const float*)d_in[1];
  const float* tl    = (const float*)d_in[2];
  const float* tr    = (const float*)d_in[3];
  const float* queue = (const float*)d_in[4];
  float* out = (float*)d_out;
  float* ws = (float*)d_ws;

  float* qInv = ws;                          // 6016
  float* S    = ws + 6016;                   // 16384
  float* lg0  = ws + 22400;                  // 16384
  float* mk   = ws + 38784;                  // 16384
  float* xr   = ws + 55168;                  // 16384 -> 71552
  int* count  = (int*)(ws + 71552);          // 1
  int* list   = (int*)(ws + 71568);          // 16384 -> 87952
  _Float16* QTf     = (_Float16*)(ws + 88064);    // NPIX*128 f16  (1048576 fl)
  _Float16* queueTf = (_Float16*)(ws + 1136640);  // 6016*128 f16  (385024 fl)
  _Float16* tgtTf   = (_Float16*)(ws + 1521664);  // NPIX*128 f16  (1048576 fl)
  _Float16* refTf   = (_Float16*)(ws + 2570240);  // NPIX*128 f16  (1048576 fl)

  // JAX: k1, k2 = split(key(1234))
  uint32_t b0o0, b0o1, b1o0, b1o1;
  threefry2x32(0u, 1234u, 0u, 2u, &b0o0, &b0o1);
  threefry2x32(0u, 1234u, 1u, 3u, &b1o0, &b1o1);
  uint32_t k1a = b0o0, k1b = b1o0, k2a = b0o1, k2b = b1o1;

  k_transpose<<<dim3(HWFM / 32, CFM / 32, 4), dim3(32, 8), 0, stream>>>(ref, tgt, refTf, tgtTf);
  k_qtrans<<<dim3(KQPAD / 32, CFM / 32), dim3(32, 8), 0, stream>>>(queue, queueTf);
  k_qnorms_init<<<dim3((KQ + 255) / 256), dim3(256), 0, stream>>>(queue, qInv, count);
  k_prelude<<<dim3(NPIX / 4), dim3(256), 0, stream>>>(tl, tr, refTf, tgtTf, QTf, S, lg0, mk, xr, count, list);
  k_negatives_mfma<<<dim3(NPIX / 4), dim3(256), 0, stream>>>(QTf, tgtTf, xr, S, count, list, k1a, k1b, k2a, k2b);
  k_gemm_mfma<<<dim3(KQPAD / 128, NPIX / 64), dim3(256), 0, stream>>>(QTf, queueTf, qInv, S, count, list);
  k_finalize<<<dim3(1), dim3(256), 0, stream>>>(S, lg0, mk, out);
}

// Round 6
// 203.286 us; speedup vs baseline: 4.5749x; 1.4306x over previous
//
#include <hip/hip_runtime.h>
#include <stdint.h>
#include <math.h>

#define HFM 64
#define WFM 128
#define CFM 128
#define BN 2
#define HWFM (HFM*WFM)          // 8192
#define NPIX (BN*HWFM)          // 16384
#define KQ 6000
#define KQPAD 6016
#define NNEG 60
#define NE (NPIX*NNEG)          // 983040
#define EHALF_U 491520u
#define MSHIFT 15.0f

typedef _Float16 f16_8 __attribute__((ext_vector_type(8)));
typedef _Float16 f16_2 __attribute__((ext_vector_type(2)));
typedef float f32_4 __attribute__((ext_vector_type(4)));

// ---------------- JAX threefry2x32 (bit-exact) ----------------
__host__ __device__ __forceinline__ void threefry2x32(uint32_t k0, uint32_t k1,
                                                      uint32_t x0, uint32_t x1,
                                                      uint32_t* o0, uint32_t* o1) {
  uint32_t ks2 = k0 ^ k1 ^ 0x1BD11BDAu;
  x0 += k0; x1 += k1;
#define TFR(r) { x0 += x1; x1 = (x1 << (r)) | (x1 >> (32 - (r))); x1 ^= x0; }
  TFR(13) TFR(15) TFR(26) TFR(6)
  x0 += k1;  x1 += ks2 + 1u;
  TFR(17) TFR(29) TFR(16) TFR(24)
  x0 += ks2; x1 += k0 + 2u;
  TFR(13) TFR(15) TFR(26) TFR(6)
  x0 += k0;  x1 += k1 + 3u;
  TFR(17) TFR(29) TFR(16) TFR(24)
  x0 += k1;  x1 += ks2 + 4u;
  TFR(13) TFR(15) TFR(26) TFR(6)
  x0 += ks2; x1 += k0 + 5u;
#undef TFR
  *o0 = x0; *o1 = x1;
}

// grid_sample coordinate helper (reference op order)
__device__ __forceinline__ void gs_coord(float t, float halfdim, float maxc,
                                         int* i0, int* i1, float* w) {
  float g = 2.0f * t - 1.0f;
  float x = (g + 1.0f) * halfdim - 0.5f;
  x = fminf(fmaxf(x, 0.0f), maxc);
  float f = floorf(x);
  *i0 = (int)f;
  *w = x - f;
  *i1 = (int)fminf(f + 1.0f, maxc);
}

// ref [b,c,hw] -> refTf f16 [b,hw,c];  tgt [b,c,hw] -> tgtTf f16 [b,hw,c]
__global__ void k_transpose(const float* __restrict__ ref, const float* __restrict__ tgt,
                            _Float16* __restrict__ refTf, _Float16* __restrict__ tgtTf) {
  __shared__ float tile[32][33];
  int z = blockIdx.z;
  int arr = z >> 1, b = z & 1;
  const float* src = (arr == 0 ? ref : tgt) + (size_t)b * CFM * HWFM;
  _Float16* dst = (arr == 0 ? refTf : tgtTf) + (size_t)b * HWFM * CFM;
  int x0 = blockIdx.x * 32;   // hw
  int y0 = blockIdx.y * 32;   // c
  int tx = threadIdx.x, ty = threadIdx.y;
#pragma unroll
  for (int i = 0; i < 32; i += 8)
    tile[ty + i][tx] = src[(size_t)(y0 + ty + i) * HWFM + x0 + tx];
  __syncthreads();
#pragma unroll
  for (int i = 0; i < 32; i += 8)
    dst[(size_t)(x0 + ty + i) * CFM + (y0 + tx)] = (_Float16)tile[tx][ty + i];
}

// transpose queue [128][6000] fp32 -> [6016][128] f16 (rows 6000..6015 zero)
__global__ void k_qtrans(const float* __restrict__ queue, _Float16* __restrict__ queueTf) {
  __shared__ float tile[32][33];
  int n0 = blockIdx.x * 32;   // queue col
  int c0 = blockIdx.y * 32;   // channel
  int tx = threadIdx.x, ty = threadIdx.y;
#pragma unroll
  for (int i = 0; i < 32; i += 8) {
    int n = n0 + tx;
    tile[ty + i][tx] = (n < KQ) ? queue[(size_t)(c0 + ty + i) * KQ + n] : 0.0f;
  }
  __syncthreads();
#pragma unroll
  for (int i = 0; i < 32; i += 8)
    queueTf[(size_t)(n0 + ty + i) * CFM + (c0 + tx)] = (_Float16)tile[tx][ty + i];
}

// queue column inv-norms
__global__ void k_qnorms(const float* __restrict__ queue, float* __restrict__ qInv) {
  int k = blockIdx.x * 256 + threadIdx.x;
  if (k >= KQ) return;
  float ss = 0.0f;
  for (int c = 0; c < CFM; c++) { float v = queue[c * KQ + k]; ss += v * v; }
  qInv[k] = 1.0f / fmaxf(sqrtf(ss), 1e-12f);
}

// per pixel (wave-per-pixel): mask; if unmasked: fused query normalize,
// positive dot, l_pos, xr, S store. NO global atomics (compaction is separate).
__global__ __launch_bounds__(256) void k_prelude(
    const float* __restrict__ target_l, const float* __restrict__ target_r,
    const _Float16* __restrict__ refTf, const _Float16* __restrict__ tgtTf,
    _Float16* __restrict__ QTf,
    float* __restrict__ S, float* __restrict__ logit0,
    float* __restrict__ maskArr, float* __restrict__ xr) {
  int tid = threadIdx.x;
  int wave = tid >> 6, lane = tid & 63;
  int p = blockIdx.x * 4 + wave;
  int b = p >> 13;
  int rem = p & (HWFM - 1);
  int i = rem >> 7, j = rem & 127;
  const float stepx = 1.0f / 127.0f, stepy = 1.0f / 63.0f;
  float xb = (j == 127) ? 1.0f : j * stepx;
  float yb = (i == 63) ? 1.0f : i * stepy;
  const float* tl = target_l + (size_t)b * 256 * 512;
  const float* tr = target_r + (size_t)b * 256 * 512;

  // eager: query row load (independent of everything)
  int c2 = lane * 2;
  f16_2 q2 = *(const f16_2*)(refTf + (size_t)p * CFM + c2);

  float dl = tl[(4 * i) * 512 + 4 * j] * 0.25f;   // broadcast load

  int y0i, y1i; float wy;
  gs_coord(yb, 32.0f, 63.0f, &y0i, &y1i, &wy);
  float t = xb - dl * (1.0f / 128.0f);
  int x0i, x1i; float wx;
  gs_coord(t, 64.0f, 127.0f, &x0i, &x1i, &wx);

  // eager: positive-sample feature loads (issue in parallel with innerv math)
  int bo = b * HWFM;
  f16_2 a2 = *(const f16_2*)(tgtTf + (size_t)(bo + y0i * WFM + x0i) * CFM + c2);
  f16_2 b2 = *(const f16_2*)(tgtTf + (size_t)(bo + y0i * WFM + x1i) * CFM + c2);
  f16_2 cc2 = *(const f16_2*)(tgtTf + (size_t)(bo + y1i * WFM + x0i) * CFM + c2);
  f16_2 d2 = *(const f16_2*)(tgtTf + (size_t)(bo + y1i * WFM + x1i) * CFM + c2);

  auto innerv = [&](int y, int x) -> float {
    float xbx = (x == 127) ? 1.0f : x * stepx;
    float drv = tr[(4 * y) * 512 + 4 * x] * 0.25f;  // broadcast load
    float ti = xbx + drv * (1.0f / 128.0f);
    float g = 2.0f * ti - 1.0f;
    float ix2 = fminf(fmaxf((g + 1.0f) * 64.0f - 0.5f, 0.0f), 127.0f);
    float x0f = floorf(ix2);
    float wxp = ix2 - x0f;
    float x1f = fminf(x0f + 1.0f, 127.0f);
    return x0f * (1.0f - wxp) + x1f * wxp;
  };
  float v00 = innerv(y0i, x0i), v01 = innerv(y0i, x1i);
  float v10 = innerv(y1i, x0i), v11 = innerv(y1i, x1i);
  float l2r2l = v00 * (1.0f - wx) * (1.0f - wy) + v01 * wx * (1.0f - wy)
              + v10 * (1.0f - wx) * wy + v11 * wx * wy;
  bool masko = fabsf((float)j - l2r2l) < 3.0f;
  bool mk = masko && (dl > 0.0f) && (t >= 0.0f);
  if (lane == 0) maskArr[p] = mk ? 1.0f : 0.0f;
  if (!mk) return;   // wave-uniform

  // bilinear blend
  float w00 = (1.0f - wx) * (1.0f - wy), w01 = wx * (1.0f - wy);
  float w10 = (1.0f - wx) * wy,          w11 = wx * wy;
  float q0 = (float)q2[0], q1 = (float)q2[1];
  float v0 = w00 * (float)a2[0] + w01 * (float)b2[0] + w10 * (float)cc2[0] + w11 * (float)d2[0];
  float v1 = w00 * (float)a2[1] + w01 * (float)b2[1] + w10 * (float)cc2[1] + w11 * (float)d2[1];

  // single combined reduction: ssq, raw dot, ssv
  float s0 = q0 * q0 + q1 * q1;
  float s1 = q0 * v0 + q1 * v1;
  float s2 = v0 * v0 + v1 * v1;
#pragma unroll
  for (int o = 32; o; o >>= 1) {
    s0 += __shfl_xor(s0, o, 64);
    s1 += __shfl_xor(s1, o, 64);
    s2 += __shfl_xor(s2, o, 64);
  }
  float inv = 1.0f / fmaxf(sqrtf(s0), 1e-12f);
  f16_2 qw; qw[0] = (_Float16)(q0 * inv); qw[1] = (_Float16)(q1 * inv);
  *(f16_2*)(QTf + (size_t)p * CFM + c2) = qw;
  if (lane == 0) {
    float lpos = (s1 * inv) / fmaxf(sqrtf(s2), 1e-12f);
    float lg0 = lpos / 0.07f;
    logit0[p] = lg0;
    xr[p] = t * 128.0f;
    S[p] = expf(lg0 - MSHIFT);   // first writer; later kernels atomicAdd
  }
}

// single-block ballot + prefix-scan compaction (ascending pixel order)
__global__ __launch_bounds__(1024) void k_compact(const float* __restrict__ maskArr,
                                                  int* __restrict__ count,
                                                  int* __restrict__ list) {
  int tid = threadIdx.x;             // 0..1023, each handles 16 consecutive pixels
  int lane = tid & 63, wave = tid >> 6;
  int base_p = tid * 16;
  const float4* m4 = (const float4*)(maskArr + base_p);
  float4 v[4];
#pragma unroll
  for (int k = 0; k < 4; k++) v[k] = m4[k];
  unsigned int bits = 0;
#pragma unroll
  for (int k = 0; k < 4; k++) {
    if (v[k].x > 0.0f) bits |= 1u << (4 * k + 0);
    if (v[k].y > 0.0f) bits |= 1u << (4 * k + 1);
    if (v[k].z > 0.0f) bits |= 1u << (4 * k + 2);
    if (v[k].w > 0.0f) bits |= 1u << (4 * k + 3);
  }
  int m = __popc(bits);
  int scan = m;   // inclusive scan within wave
#pragma unroll
  for (int off = 1; off < 64; off <<= 1) {
    int n = __shfl_up(scan, off, 64);
    if (lane >= off) scan += n;
  }
  __shared__ int wsum[16];
  if (lane == 63) wsum[wave] = scan;
  __syncthreads();
  int wbase = 0;
  for (int w = 0; w < wave; w++) wbase += wsum[w];
  int idx = wbase + scan - m;   // exclusive prefix for this thread
#pragma unroll
  for (int k = 0; k < 16; k++) {
    if (bits & (1u << k)) list[idx++] = base_p + k;
  }
  if (tid == 1023) *count = idx;
}

// -------- negatives: wave-per-(compacted)pixel, MFMA reduction --------
__global__ __launch_bounds__(256) void k_negatives_mfma(
    const _Float16* __restrict__ QTf, const _Float16* __restrict__ tgtTf,
    const float* __restrict__ xr, float* __restrict__ S,
    const int* __restrict__ count, const int* __restrict__ list,
    uint32_t k1a, uint32_t k1b, uint32_t k2a, uint32_t k2b) {
  int tid = threadIdx.x;
  int wave = tid >> 6;
  int lane = tid & 63;
  int quad = lane >> 4;
  int l16 = lane & 15;
  int cnt = *count;
  int slot = blockIdx.x * 4 + wave;
  if (slot >= cnt) return;
  int p = list[slot];
  int b = p >> 13;

  // ---- Phase A: per-lane RNG for negative n = lane ----
  uint32_t e = (uint32_t)(p * NNEG + lane);
  uint32_t h0, h1;
  threefry2x32(k1a, k1b, e, e + (uint32_t)NE, &h0, &h1);
  uint32_t off = ((h0 % 24u) * 16u + (h1 % 24u)) % 24u;
  float mag = (float)(1u + off);
  uint32_t ub;
  {
    uint32_t a, bm;
    if (e < EHALF_U) { threefry2x32(k2a, k2b, e, e + EHALF_U, &a, &bm); ub = a; }
    else             { threefry2x32(k2a, k2b, e - EHALF_U, e, &a, &bm); ub = bm; }
  }
  float u = __uint_as_float((ub >> 9) | 0x3F800000u) - 1.0f;
  float sg = (u > 0.5f) ? 1.0f : ((u < 0.5f) ? -1.0f : 0.0f);

  float xrp = xr[p];
  float v = xrp + mag * sg;
  float r = fmodf(v, 128.0f);
  if (r < 0.0f) r += 128.0f;
  float fx = r * (1.0f / 128.0f);
  float fy = fx * (1.0f / 64.0f);
  int x0i, x1i, y0i, y1i; float wx, wy;
  gs_coord(fx, 64.0f, 127.0f, &x0i, &x1i, &wx);
  gs_coord(fy, 32.0f, 63.0f, &y0i, &y1i, &wy);   // y0=0, y1=1 always here
  float w00 = (1.0f - wx) * (1.0f - wy), w01 = wx * (1.0f - wy);
  float w10 = (1.0f - wx) * wy,          w11 = wx * wy;

  // ---- Phase B ---- (compacted => mask == 1)
  const float mask_p = 1.0f / 0.07f;
  const _Float16* qrow = QTf + (size_t)p * CFM;
  f16_8 Qf[4];
#pragma unroll
  for (int s = 0; s < 4; s++)
    Qf[s] = *(const f16_8*)(qrow + s * 32 + quad * 8);

  const _Float16* tb0 = tgtTf + (size_t)(b * HWFM) * CFM;        // y=0 rows
  const _Float16* tb1 = tgtTf + (size_t)(b * HWFM + WFM) * CFM;  // y=1 rows
  float esum = 0.0f;

#pragma unroll
  for (int g = 0; g < 4; g++) {
    int srcl = g * 16 + l16;
    float gw00 = __shfl(w00, srcl, 64);
    float gw01 = __shfl(w01, srcl, 64);
    float gw10 = __shfl(w10, srcl, 64);
    float gw11 = __shfl(w11, srcl, 64);
    int gx0 = __shfl(x0i, srcl, 64);
    int gx1 = __shfl(x1i, srcl, 64);
    const _Float16* r00 = tb0 + (size_t)gx0 * CFM;
    const _Float16* r01 = tb0 + (size_t)gx1 * CFM;
    const _Float16* r10 = tb1 + (size_t)gx0 * CFM;
    const _Float16* r11 = tb1 + (size_t)gx1 * CFM;

    f32_4 accD = (f32_4){0.0f, 0.0f, 0.0f, 0.0f};
    f32_4 accS = (f32_4){0.0f, 0.0f, 0.0f, 0.0f};
#pragma unroll
    for (int s = 0; s < 4; s++) {
      int ch = s * 32 + quad * 8;
      f16_8 a8 = *(const f16_8*)(r00 + ch);
      f16_8 b8 = *(const f16_8*)(r01 + ch);
      f16_8 c8 = *(const f16_8*)(r10 + ch);
      f16_8 d8 = *(const f16_8*)(r11 + ch);
      f16_8 vf;
#pragma unroll
      for (int jj = 0; jj < 8; jj++) {
        float vv = gw00 * (float)a8[jj] + gw01 * (float)b8[jj]
                 + gw10 * (float)c8[jj] + gw11 * (float)d8[jj];
        vf[jj] = (_Float16)vv;
      }
      accD = __builtin_amdgcn_mfma_f32_16x16x32_f16(vf, Qf[s], accD, 0, 0, 0);
      accS = __builtin_amdgcn_mfma_f32_16x16x32_f16(vf, vf, accS, 0, 0, 0);
    }
    // diagonal lanes: row (quad*4+reg) == col l16
    if ((l16 >> 2) == quad) {
      int rg = l16 & 3;
      int n_g = g * 16 + l16;
      if (n_g < NNEG) {
        float dot = accD[rg], ssn = accS[rg];
        float ln = dot / fmaxf(sqrtf(ssn), 1e-12f);
        float lg = ln * mask_p;
        esum += __expf(lg - MSHIFT);
      }
    }
  }
#pragma unroll
  for (int o = 32; o; o >>= 1) esum += __shfl_xor(esum, o, 64);
  if (lane == 0) atomicAdd(&S[p], esum);
}

// -------- MFMA l_q GEMM over compacted rows, fused with exp-sum --------
__global__ __launch_bounds__(256) void k_gemm_mfma(
    const _Float16* __restrict__ QTf,     // [NPIX][128]
    const _Float16* __restrict__ queueTf, // [6016][128]
    const float* __restrict__ qInv,
    float* __restrict__ S,
    const int* __restrict__ count, const int* __restrict__ list) {
  __shared__ float Srow[64];
  int tid = threadIdx.x;
  int cnt = *count;
  if ((int)(blockIdx.y * 64) >= cnt) return;   // block-uniform early exit
  int wave = tid >> 6;
  int lane = tid & 63;
  int quad = lane >> 4;
  int l16 = lane & 15;
  int wm = wave >> 1;
  int wn = wave & 1;
  int p0 = blockIdx.y * 64 + wm * 32;
  int n0 = blockIdx.x * 128 + wn * 64;

  if (tid < 64) Srow[tid] = 0.0f;

  // indirect A rows
  int prow[2];
#pragma unroll
  for (int mt = 0; mt < 2; mt++)
    prow[mt] = list[min(p0 + mt * 16 + l16, cnt - 1)];

  f16_8 Af[2][4];
#pragma unroll
  for (int mt = 0; mt < 2; mt++) {
    const _Float16* arow = QTf + (size_t)prow[mt] * CFM + quad * 8;
#pragma unroll
    for (int ks = 0; ks < 4; ks++)
      Af[mt][ks] = *(const f16_8*)(arow + ks * 32);
  }

  f16_8 Bf[4][4];
  const _Float16* brow = queueTf + (size_t)(n0 + l16) * CFM + quad * 8;
#pragma unroll
  for (int nt = 0; nt < 4; nt++)
#pragma unroll
    for (int ks = 0; ks < 4; ks++)
      Bf[nt][ks] = *(const f16_8*)(brow + (size_t)nt * 16 * CFM + ks * 32);

  f32_4 acc[2][4];
#pragma unroll
  for (int mt = 0; mt < 2; mt++)
#pragma unroll
    for (int nt = 0; nt < 4; nt++)
      acc[mt][nt] = (f32_4){0.0f, 0.0f, 0.0f, 0.0f};

#pragma unroll
  for (int ks = 0; ks < 4; ks++)
#pragma unroll
    for (int mt = 0; mt < 2; mt++)
#pragma unroll
      for (int nt = 0; nt < 4; nt++)
        acc[mt][nt] = __builtin_amdgcn_mfma_f32_16x16x32_f16(Af[mt][ks], Bf[nt][ks], acc[mt][nt], 0, 0, 0);

  // compacted => mask = 1 for valid rows; 0 weight for pad rows
  float mrow[2][4];
#pragma unroll
  for (int mt = 0; mt < 2; mt++)
#pragma unroll
    for (int r = 0; r < 4; r++)
      mrow[mt][r] = (p0 + mt * 16 + quad * 4 + r < cnt) ? (1.0f / 0.07f) : 0.0f;

  float rowsum[2][4] = {{0.0f,0.0f,0.0f,0.0f},{0.0f,0.0f,0.0f,0.0f}};
#pragma unroll
  for (int nt = 0; nt < 4; nt++) {
    int n = n0 + nt * 16 + l16;
    bool valid = n < KQ;
    float qi = valid ? qInv[n] : 0.0f;
#pragma unroll
    for (int mt = 0; mt < 2; mt++)
#pragma unroll
      for (int r = 0; r < 4; r++) {
        float lg = acc[mt][nt][r] * qi * mrow[mt][r];
        float ev = valid ? __expf(lg - MSHIFT) : 0.0f;
        rowsum[mt][r] += ev;
      }
  }
#pragma unroll
  for (int mt = 0; mt < 2; mt++)
#pragma unroll
    for (int r = 0; r < 4; r++) {
      float vv = rowsum[mt][r];
      vv += __shfl_xor(vv, 1);
      vv += __shfl_xor(vv, 2);
      vv += __shfl_xor(vv, 4);
      vv += __shfl_xor(vv, 8);
      rowsum[mt][r] = vv;
    }
  __syncthreads();
  if (l16 == 0) {
#pragma unroll
    for (int mt = 0; mt < 2; mt++)
#pragma unroll
      for (int r = 0; r < 4; r++)
        atomicAdd(&Srow[wm * 32 + mt * 16 + quad * 4 + r], rowsum[mt][r]);
  }
  __syncthreads();
  if (tid < 64) {
    int pr = blockIdx.y * 64 + tid;
    if (pr < cnt) atomicAdd(&S[list[pr]], Srow[tid]);
  }
}

__global__ __launch_bounds__(1024) void k_finalize(
    const float* __restrict__ S, const float* __restrict__ logit0,
    const float* __restrict__ maskArr, float* __restrict__ out) {
  int tid = threadIdx.x;
  const float cmask = logf(6061.0f);   // masked row: all 6061 logits are exactly 0
  double acc = 0.0;
  for (int p = tid; p < NPIX; p += 1024) {
    float term = (maskArr[p] > 0.0f) ? (logf(S[p]) + MSHIFT - logit0[p]) : cmask;
    acc += (double)term;
  }
#pragma unroll
  for (int off = 32; off; off >>= 1) acc += __shfl_down(acc, off, 64);
  __shared__ double sd[16];
  if ((tid & 63) == 0) sd[tid >> 6] = acc;
  __syncthreads();
  if (tid == 0) {
    double tot = 0.0;
    for (int w = 0; w < 16; w++) tot += sd[w];
    out[0] = (float)(tot / (double)NPIX);
  }
}

extern "C" void kernel_launch(void* const* d_in, const int* in_sizes, int n_in,
                              void* d_out, int out_size, void* d_ws, size_t ws_size,
                              hipStream_t stream) {
  const float* ref   = (const float*)d_in[0];
  const float* tgt   = (const float*)d_in[1];
  const float* tl    = (const float*)d_in[2];
  const float* tr    = (const float*)d_in[3];
  const float* queue = (const float*)d_in[4];
  float* out = (float*)d_out;
  float* ws = (float*)d_ws;

  float* qInv = ws;                          // 6016
  float* S    = ws + 6016;                   // 16384
  float* lg0  = ws + 22400;                  // 16384
  float* mk   = ws + 38784;                  // 16384
  float* xr   = ws + 55168;                  // 16384 -> 71552
  int* count  = (int*)(ws + 71552);          // 1
  int* list   = (int*)(ws + 71568);          // 16384 -> 87952
  _Float16* QTf     = (_Float16*)(ws + 88064);    // NPIX*128 f16  (1048576 fl)
  _Float16* queueTf = (_Float16*)(ws + 1136640);  // 6016*128 f16  (385024 fl)
  _Float16* tgtTf   = (_Float16*)(ws + 1521664);  // NPIX*128 f16  (1048576 fl)
  _Float16* refTf   = (_Float16*)(ws + 2570240);  // NPIX*128 f16  (1048576 fl)

  // JAX: k1, k2 = split(key(1234))
  uint32_t b0o0, b0o1, b1o0, b1o1;
  threefry2x32(0u, 1234u, 0u, 2u, &b0o0, &b0o1);
  threefry2x32(0u, 1234u, 1u, 3u, &b1o0, &b1o1);
  uint32_t k1a = b0o0, k1b = b1o0, k2a = b0o1, k2b = b1o1;

  k_transpose<<<dim3(HWFM / 32, CFM / 32, 4), dim3(32, 8), 0, stream>>>(ref, tgt, refTf, tgtTf);
  k_qtrans<<<dim3(KQPAD / 32, CFM / 32), dim3(32, 8), 0, stream>>>(queue, queueTf);
  k_qnorms<<<dim3((KQ + 255) / 256), dim3(256), 0, stream>>>(queue, qInv);
  k_prelude<<<dim3(NPIX / 4), dim3(256), 0, stream>>>(tl, tr, refTf, tgtTf, QTf, S, lg0, mk, xr);
  k_compact<<<dim3(1), dim3(1024), 0, stream>>>(mk, count, list);
  k_negatives_mfma<<<dim3(NPIX / 4), dim3(256), 0, stream>>>(QTf, tgtTf, xr, S, count, list, k1a, k1b, k2a, k2b);
  k_gemm_mfma<<<dim3(KQPAD / 128, NPIX / 64), dim3(256), 0, stream>>>(QTf, queueTf, qInv, S, count, list);
  k_finalize<<<dim3(1), dim3(1024), 0, stream>>>(S, lg0, mk, out);
}

// Round 7
// 185.992 us; speedup vs baseline: 5.0003x; 1.0930x over previous
//
#include <hip/hip_runtime.h>
#include <stdint.h>
#include <math.h>

#define HFM 64
#define WFM 128
#define CFM 128
#define BN 2
#define HWFM (HFM*WFM)          // 8192
#define NPIX (BN*HWFM)          // 16384
#define KQ 6000
#define KQP 6144                // padded to 48*128 (rows 6000..6143 zero)
#define NNEG 60
#define NE (NPIX*NNEG)          // 983040
#define EHALF_U 491520u
#define MSHIFT 15.0f

typedef _Float16 f16_8 __attribute__((ext_vector_type(8)));
typedef _Float16 f16_2 __attribute__((ext_vector_type(2)));
typedef float f32_4 __attribute__((ext_vector_type(4)));

// ---------------- JAX threefry2x32 (bit-exact) ----------------
__host__ __device__ __forceinline__ void threefry2x32(uint32_t k0, uint32_t k1,
                                                      uint32_t x0, uint32_t x1,
                                                      uint32_t* o0, uint32_t* o1) {
  uint32_t ks2 = k0 ^ k1 ^ 0x1BD11BDAu;
  x0 += k0; x1 += k1;
#define TFR(r) { x0 += x1; x1 = (x1 << (r)) | (x1 >> (32 - (r))); x1 ^= x0; }
  TFR(13) TFR(15) TFR(26) TFR(6)
  x0 += k1;  x1 += ks2 + 1u;
  TFR(17) TFR(29) TFR(16) TFR(24)
  x0 += ks2; x1 += k0 + 2u;
  TFR(13) TFR(15) TFR(26) TFR(6)
  x0 += k0;  x1 += k1 + 3u;
  TFR(17) TFR(29) TFR(16) TFR(24)
  x0 += k1;  x1 += ks2 + 4u;
  TFR(13) TFR(15) TFR(26) TFR(6)
  x0 += ks2; x1 += k0 + 5u;
#undef TFR
  *o0 = x0; *o1 = x1;
}

// grid_sample coordinate helper (reference op order)
__device__ __forceinline__ void gs_coord(float t, float halfdim, float maxc,
                                         int* i0, int* i1, float* w) {
  float g = 2.0f * t - 1.0f;
  float x = (g + 1.0f) * halfdim - 0.5f;
  x = fminf(fmaxf(x, 0.0f), maxc);
  float f = floorf(x);
  *i0 = (int)f;
  *w = x - f;
  *i1 = (int)fminf(f + 1.0f, maxc);
}

// ref [b,c,hw] -> refTf f16 [b,hw,c];  tgt [b,c,hw] -> tgtTf f16 [b,hw,c]
__global__ void k_transpose(const float* __restrict__ ref, const float* __restrict__ tgt,
                            _Float16* __restrict__ refTf, _Float16* __restrict__ tgtTf) {
  __shared__ float tile[32][33];
  int z = blockIdx.z;
  int arr = z >> 1, b = z & 1;
  const float* src = (arr == 0 ? ref : tgt) + (size_t)b * CFM * HWFM;
  _Float16* dst = (arr == 0 ? refTf : tgtTf) + (size_t)b * HWFM * CFM;
  int x0 = blockIdx.x * 32;   // hw
  int y0 = blockIdx.y * 32;   // c
  int tx = threadIdx.x, ty = threadIdx.y;
#pragma unroll
  for (int i = 0; i < 32; i += 8)
    tile[ty + i][tx] = src[(size_t)(y0 + ty + i) * HWFM + x0 + tx];
  __syncthreads();
#pragma unroll
  for (int i = 0; i < 32; i += 8)
    dst[(size_t)(x0 + ty + i) * CFM + (y0 + tx)] = (_Float16)tile[tx][ty + i];
}

// transpose queue [128][6000] fp32 -> [6144][128] f16 (rows 6000..6143 zero)
__global__ void k_qtrans(const float* __restrict__ queue, _Float16* __restrict__ queueTf) {
  __shared__ float tile[32][33];
  int n0 = blockIdx.x * 32;   // queue col
  int c0 = blockIdx.y * 32;   // channel
  int tx = threadIdx.x, ty = threadIdx.y;
#pragma unroll
  for (int i = 0; i < 32; i += 8) {
    int n = n0 + tx;
    tile[ty + i][tx] = (n < KQ) ? queue[(size_t)(c0 + ty + i) * KQ + n] : 0.0f;
  }
  __syncthreads();
#pragma unroll
  for (int i = 0; i < 32; i += 8)
    queueTf[(size_t)(n0 + ty + i) * CFM + (c0 + tx)] = (_Float16)tile[tx][ty + i];
}

// queue column inv-norms (zero for pad columns)
__global__ void k_qnorms(const float* __restrict__ queue, float* __restrict__ qInv) {
  int k = blockIdx.x * 256 + threadIdx.x;
  if (k >= KQP) return;
  if (k >= KQ) { qInv[k] = 0.0f; return; }
  float ss = 0.0f;
  for (int c = 0; c < CFM; c++) { float v = queue[c * KQ + k]; ss += v * v; }
  qInv[k] = 1.0f / fmaxf(sqrtf(ss), 1e-12f);
}

// per pixel (wave-per-pixel): mask; if unmasked: fused query normalize,
// positive dot, l_pos, xr, S store. NO global atomics (compaction is separate).
__global__ __launch_bounds__(256) void k_prelude(
    const float* __restrict__ target_l, const float* __restrict__ target_r,
    const _Float16* __restrict__ refTf, const _Float16* __restrict__ tgtTf,
    _Float16* __restrict__ QTf,
    float* __restrict__ S, float* __restrict__ logit0,
    float* __restrict__ maskArr, float* __restrict__ xr) {
  int tid = threadIdx.x;
  int wave = tid >> 6, lane = tid & 63;
  int p = blockIdx.x * 4 + wave;
  int b = p >> 13;
  int rem = p & (HWFM - 1);
  int i = rem >> 7, j = rem & 127;
  const float stepx = 1.0f / 127.0f, stepy = 1.0f / 63.0f;
  float xb = (j == 127) ? 1.0f : j * stepx;
  float yb = (i == 63) ? 1.0f : i * stepy;
  const float* tl = target_l + (size_t)b * 256 * 512;
  const float* tr = target_r + (size_t)b * 256 * 512;

  // eager: query row load (independent of everything)
  int c2 = lane * 2;
  f16_2 q2 = *(const f16_2*)(refTf + (size_t)p * CFM + c2);

  float dl = tl[(4 * i) * 512 + 4 * j] * 0.25f;   // broadcast load

  int y0i, y1i; float wy;
  gs_coord(yb, 32.0f, 63.0f, &y0i, &y1i, &wy);
  float t = xb - dl * (1.0f / 128.0f);
  int x0i, x1i; float wx;
  gs_coord(t, 64.0f, 127.0f, &x0i, &x1i, &wx);

  // eager: positive-sample feature loads (issue in parallel with innerv math)
  int bo = b * HWFM;
  f16_2 a2 = *(const f16_2*)(tgtTf + (size_t)(bo + y0i * WFM + x0i) * CFM + c2);
  f16_2 b2 = *(const f16_2*)(tgtTf + (size_t)(bo + y0i * WFM + x1i) * CFM + c2);
  f16_2 cc2 = *(const f16_2*)(tgtTf + (size_t)(bo + y1i * WFM + x0i) * CFM + c2);
  f16_2 d2 = *(const f16_2*)(tgtTf + (size_t)(bo + y1i * WFM + x1i) * CFM + c2);

  auto innerv = [&](int y, int x) -> float {
    float xbx = (x == 127) ? 1.0f : x * stepx;
    float drv = tr[(4 * y) * 512 + 4 * x] * 0.25f;  // broadcast load
    float ti = xbx + drv * (1.0f / 128.0f);
    float g = 2.0f * ti - 1.0f;
    float ix2 = fminf(fmaxf((g + 1.0f) * 64.0f - 0.5f, 0.0f), 127.0f);
    float x0f = floorf(ix2);
    float wxp = ix2 - x0f;
    float x1f = fminf(x0f + 1.0f, 127.0f);
    return x0f * (1.0f - wxp) + x1f * wxp;
  };
  float v00 = innerv(y0i, x0i), v01 = innerv(y0i, x1i);
  float v10 = innerv(y1i, x0i), v11 = innerv(y1i, x1i);
  float l2r2l = v00 * (1.0f - wx) * (1.0f - wy) + v01 * wx * (1.0f - wy)
              + v10 * (1.0f - wx) * wy + v11 * wx * wy;
  bool masko = fabsf((float)j - l2r2l) < 3.0f;
  bool mk = masko && (dl > 0.0f) && (t >= 0.0f);
  if (lane == 0) maskArr[p] = mk ? 1.0f : 0.0f;
  if (!mk) return;   // wave-uniform

  // bilinear blend
  float w00 = (1.0f - wx) * (1.0f - wy), w01 = wx * (1.0f - wy);
  float w10 = (1.0f - wx) * wy,          w11 = wx * wy;
  float q0 = (float)q2[0], q1 = (float)q2[1];
  float v0 = w00 * (float)a2[0] + w01 * (float)b2[0] + w10 * (float)cc2[0] + w11 * (float)d2[0];
  float v1 = w00 * (float)a2[1] + w01 * (float)b2[1] + w10 * (float)cc2[1] + w11 * (float)d2[1];

  // single combined reduction: ssq, raw dot, ssv
  float s0 = q0 * q0 + q1 * q1;
  float s1 = q0 * v0 + q1 * v1;
  float s2 = v0 * v0 + v1 * v1;
#pragma unroll
  for (int o = 32; o; o >>= 1) {
    s0 += __shfl_xor(s0, o, 64);
    s1 += __shfl_xor(s1, o, 64);
    s2 += __shfl_xor(s2, o, 64);
  }
  float inv = 1.0f / fmaxf(sqrtf(s0), 1e-12f);
  f16_2 qw; qw[0] = (_Float16)(q0 * inv); qw[1] = (_Float16)(q1 * inv);
  *(f16_2*)(QTf + (size_t)p * CFM + c2) = qw;
  if (lane == 0) {
    float lpos = (s1 * inv) / fmaxf(sqrtf(s2), 1e-12f);
    float lg0 = lpos / 0.07f;
    logit0[p] = lg0;
    xr[p] = t * 128.0f;
    S[p] = expf(lg0 - MSHIFT);   // first writer; later kernels atomicAdd
  }
}

// single-block ballot + prefix-scan compaction (ascending pixel order)
__global__ __launch_bounds__(1024) void k_compact(const float* __restrict__ maskArr,
                                                  int* __restrict__ count,
                                                  int* __restrict__ list) {
  int tid = threadIdx.x;             // 0..1023, each handles 16 consecutive pixels
  int lane = tid & 63, wave = tid >> 6;
  int base_p = tid * 16;
  const float4* m4 = (const float4*)(maskArr + base_p);
  float4 v[4];
#pragma unroll
  for (int k = 0; k < 4; k++) v[k] = m4[k];
  unsigned int bits = 0;
#pragma unroll
  for (int k = 0; k < 4; k++) {
    if (v[k].x > 0.0f) bits |= 1u << (4 * k + 0);
    if (v[k].y > 0.0f) bits |= 1u << (4 * k + 1);
    if (v[k].z > 0.0f) bits |= 1u << (4 * k + 2);
    if (v[k].w > 0.0f) bits |= 1u << (4 * k + 3);
  }
  int m = __popc(bits);
  int scan = m;   // inclusive scan within wave
#pragma unroll
  for (int off = 1; off < 64; off <<= 1) {
    int n = __shfl_up(scan, off, 64);
    if (lane >= off) scan += n;
  }
  __shared__ int wsum[16];
  if (lane == 63) wsum[wave] = scan;
  __syncthreads();
  int wbase = 0;
  for (int w = 0; w < wave; w++) wbase += wsum[w];
  int idx = wbase + scan - m;   // exclusive prefix for this thread
#pragma unroll
  for (int k = 0; k < 16; k++) {
    if (bits & (1u << k)) list[idx++] = base_p + k;
  }
  if (tid == 1023) *count = idx;
}

// -------- negatives: wave-per-(compacted)pixel, MFMA reduction --------
__global__ __launch_bounds__(256) void k_negatives_mfma(
    const _Float16* __restrict__ QTf, const _Float16* __restrict__ tgtTf,
    const float* __restrict__ xr, float* __restrict__ S,
    const int* __restrict__ count, const int* __restrict__ list,
    uint32_t k1a, uint32_t k1b, uint32_t k2a, uint32_t k2b) {
  int tid = threadIdx.x;
  int wave = tid >> 6;
  int lane = tid & 63;
  int quad = lane >> 4;
  int l16 = lane & 15;
  int cnt = *count;
  int slot = blockIdx.x * 4 + wave;
  if (slot >= cnt) return;
  int p = list[slot];
  int b = p >> 13;

  // ---- Phase A: per-lane RNG for negative n = lane ----
  uint32_t e = (uint32_t)(p * NNEG + lane);
  uint32_t h0, h1;
  threefry2x32(k1a, k1b, e, e + (uint32_t)NE, &h0, &h1);
  uint32_t off = ((h0 % 24u) * 16u + (h1 % 24u)) % 24u;
  float mag = (float)(1u + off);
  uint32_t ub;
  {
    uint32_t a, bm;
    if (e < EHALF_U) { threefry2x32(k2a, k2b, e, e + EHALF_U, &a, &bm); ub = a; }
    else             { threefry2x32(k2a, k2b, e - EHALF_U, e, &a, &bm); ub = bm; }
  }
  float u = __uint_as_float((ub >> 9) | 0x3F800000u) - 1.0f;
  float sg = (u > 0.5f) ? 1.0f : ((u < 0.5f) ? -1.0f : 0.0f);

  float xrp = xr[p];
  float v = xrp + mag * sg;
  float r = fmodf(v, 128.0f);
  if (r < 0.0f) r += 128.0f;
  float fx = r * (1.0f / 128.0f);
  float fy = fx * (1.0f / 64.0f);
  int x0i, x1i, y0i, y1i; float wx, wy;
  gs_coord(fx, 64.0f, 127.0f, &x0i, &x1i, &wx);
  gs_coord(fy, 32.0f, 63.0f, &y0i, &y1i, &wy);   // y0=0, y1=1 always here
  float w00 = (1.0f - wx) * (1.0f - wy), w01 = wx * (1.0f - wy);
  float w10 = (1.0f - wx) * wy,          w11 = wx * wy;

  // ---- Phase B ---- (compacted => mask == 1)
  const float mask_p = 1.0f / 0.07f;
  const _Float16* qrow = QTf + (size_t)p * CFM;
  f16_8 Qf[4];
#pragma unroll
  for (int s = 0; s < 4; s++)
    Qf[s] = *(const f16_8*)(qrow + s * 32 + quad * 8);

  const _Float16* tb0 = tgtTf + (size_t)(b * HWFM) * CFM;        // y=0 rows
  const _Float16* tb1 = tgtTf + (size_t)(b * HWFM + WFM) * CFM;  // y=1 rows
  float esum = 0.0f;

#pragma unroll
  for (int g = 0; g < 4; g++) {
    int srcl = g * 16 + l16;
    float gw00 = __shfl(w00, srcl, 64);
    float gw01 = __shfl(w01, srcl, 64);
    float gw10 = __shfl(w10, srcl, 64);
    float gw11 = __shfl(w11, srcl, 64);
    int gx0 = __shfl(x0i, srcl, 64);
    int gx1 = __shfl(x1i, srcl, 64);
    const _Float16* r00 = tb0 + (size_t)gx0 * CFM;
    const _Float16* r01 = tb0 + (size_t)gx1 * CFM;
    const _Float16* r10 = tb1 + (size_t)gx0 * CFM;
    const _Float16* r11 = tb1 + (size_t)gx1 * CFM;

    f32_4 accD = (f32_4){0.0f, 0.0f, 0.0f, 0.0f};
    f32_4 accS = (f32_4){0.0f, 0.0f, 0.0f, 0.0f};
#pragma unroll
    for (int s = 0; s < 4; s++) {
      int ch = s * 32 + quad * 8;
      f16_8 a8 = *(const f16_8*)(r00 + ch);
      f16_8 b8 = *(const f16_8*)(r01 + ch);
      f16_8 c8 = *(const f16_8*)(r10 + ch);
      f16_8 d8 = *(const f16_8*)(r11 + ch);
      f16_8 vf;
#pragma unroll
      for (int jj = 0; jj < 8; jj++) {
        float vv = gw00 * (float)a8[jj] + gw01 * (float)b8[jj]
                 + gw10 * (float)c8[jj] + gw11 * (float)d8[jj];
        vf[jj] = (_Float16)vv;
      }
      accD = __builtin_amdgcn_mfma_f32_16x16x32_f16(vf, Qf[s], accD, 0, 0, 0);
      accS = __builtin_amdgcn_mfma_f32_16x16x32_f16(vf, vf, accS, 0, 0, 0);
    }
    // diagonal lanes: row (quad*4+reg) == col l16
    if ((l16 >> 2) == quad) {
      int rg = l16 & 3;
      int n_g = g * 16 + l16;
      if (n_g < NNEG) {
        float dot = accD[rg], ssn = accS[rg];
        float ln = dot / fmaxf(sqrtf(ssn), 1e-12f);
        float lg = ln * mask_p;
        esum += __expf(lg - MSHIFT);
      }
    }
  }
#pragma unroll
  for (int o = 32; o; o >>= 1) esum += __shfl_xor(esum, o, 64);
  if (lane == 0) atomicAdd(&S[p], esum);
}

// -------- MFMA l_q GEMM over compacted rows, fused with exp-sum --------
// block tile 64p; loops 6 chunks of 128n (grid.x=8 covers 6144 padded cols).
__global__ __launch_bounds__(256) void k_gemm_mfma(
    const _Float16* __restrict__ QTf,     // [NPIX][128]
    const _Float16* __restrict__ queueTf, // [6144][128], rows >=6000 zero
    const float* __restrict__ qInv,       // [6144], zero for pad
    float* __restrict__ S,
    const int* __restrict__ count, const int* __restrict__ list) {
  __shared__ float Srow[64];
  int tid = threadIdx.x;
  int cnt = *count;
  if ((int)(blockIdx.y * 64) >= cnt) return;   // block-uniform early exit
  int wave = tid >> 6;
  int lane = tid & 63;
  int quad = lane >> 4;
  int l16 = lane & 15;
  int wm = wave >> 1;
  int wn = wave & 1;
  int p0 = blockIdx.y * 64 + wm * 32;

  if (tid < 64) Srow[tid] = 0.0f;

  // indirect A rows (once per block)
  int prow[2];
#pragma unroll
  for (int mt = 0; mt < 2; mt++)
    prow[mt] = list[min(p0 + mt * 16 + l16, cnt - 1)];

  f16_8 Af[2][4];
#pragma unroll
  for (int mt = 0; mt < 2; mt++) {
    const _Float16* arow = QTf + (size_t)prow[mt] * CFM + quad * 8;
#pragma unroll
    for (int ks = 0; ks < 4; ks++)
      Af[mt][ks] = *(const f16_8*)(arow + ks * 32);
  }

  float mrow[2][4];
#pragma unroll
  for (int mt = 0; mt < 2; mt++)
#pragma unroll
    for (int r = 0; r < 4; r++)
      mrow[mt][r] = (p0 + mt * 16 + quad * 4 + r < cnt) ? (1.0f / 0.07f) : 0.0f;

  float rowsum[2][4] = {{0.0f,0.0f,0.0f,0.0f},{0.0f,0.0f,0.0f,0.0f}};

  for (int ic = 0; ic < 6; ic++) {
    int n0 = (blockIdx.x * 6 + ic) * 128 + wn * 64;

    f16_8 Bf[4][4];
    const _Float16* brow = queueTf + (size_t)(n0 + l16) * CFM + quad * 8;
#pragma unroll
    for (int nt = 0; nt < 4; nt++)
#pragma unroll
      for (int ks = 0; ks < 4; ks++)
        Bf[nt][ks] = *(const f16_8*)(brow + (size_t)nt * 16 * CFM + ks * 32);

    f32_4 acc[2][4];
#pragma unroll
    for (int mt = 0; mt < 2; mt++)
#pragma unroll
      for (int nt = 0; nt < 4; nt++)
        acc[mt][nt] = (f32_4){0.0f, 0.0f, 0.0f, 0.0f};

#pragma unroll
    for (int ks = 0; ks < 4; ks++)
#pragma unroll
      for (int mt = 0; mt < 2; mt++)
#pragma unroll
        for (int nt = 0; nt < 4; nt++)
          acc[mt][nt] = __builtin_amdgcn_mfma_f32_16x16x32_f16(Af[mt][ks], Bf[nt][ks], acc[mt][nt], 0, 0, 0);

#pragma unroll
    for (int nt = 0; nt < 4; nt++) {
      int n = n0 + nt * 16 + l16;
      bool valid = n < KQ;
      float qi = qInv[n];   // zero for pad cols
#pragma unroll
      for (int mt = 0; mt < 2; mt++)
#pragma unroll
        for (int r = 0; r < 4; r++) {
          float lg = acc[mt][nt][r] * qi * mrow[mt][r];
          float ev = valid ? __expf(lg - MSHIFT) : 0.0f;
          rowsum[mt][r] += ev;
        }
    }
  }

#pragma unroll
  for (int mt = 0; mt < 2; mt++)
#pragma unroll
    for (int r = 0; r < 4; r++) {
      float vv = rowsum[mt][r];
      vv += __shfl_xor(vv, 1);
      vv += __shfl_xor(vv, 2);
      vv += __shfl_xor(vv, 4);
      vv += __shfl_xor(vv, 8);
      rowsum[mt][r] = vv;
    }
  __syncthreads();
  if (l16 == 0) {
#pragma unroll
    for (int mt = 0; mt < 2; mt++)
#pragma unroll
      for (int r = 0; r < 4; r++)
        atomicAdd(&Srow[wm * 32 + mt * 16 + quad * 4 + r], rowsum[mt][r]);
  }
  __syncthreads();
  if (tid < 64) {
    int pr = blockIdx.y * 64 + tid;
    if (pr < cnt) atomicAdd(&S[list[pr]], Srow[tid]);
  }
}

__global__ __launch_bounds__(1024) void k_finalize(
    const float* __restrict__ S, const float* __restrict__ logit0,
    const float* __restrict__ maskArr, float* __restrict__ out) {
  int tid = threadIdx.x;
  const float cmask = logf(6061.0f);   // masked row: all 6061 logits are exactly 0
  double acc = 0.0;
  for (int p = tid; p < NPIX; p += 1024) {
    float term = (maskArr[p] > 0.0f) ? (logf(S[p]) + MSHIFT - logit0[p]) : cmask;
    acc += (double)term;
  }
#pragma unroll
  for (int off = 32; off; off >>= 1) acc += __shfl_down(acc, off, 64);
  __shared__ double sd[16];
  if ((tid & 63) == 0) sd[tid >> 6] = acc;
  __syncthreads();
  if (tid == 0) {
    double tot = 0.0;
    for (int w = 0; w < 16; w++) tot += sd[w];
    out[0] = (float)(tot / (double)NPIX);
  }
}

extern "C" void kernel_launch(void* const* d_in, const int* in_sizes, int n_in,
                              void* d_out, int out_size, void* d_ws, size_t ws_size,
                              hipStream_t stream) {
  const float* ref   = (const float*)d_in[0];
  const float* tgt   = (const float*)d_in[1];
  const float* tl    = (const float*)d_in[2];
  const float* tr    = (const float*)d_in[3];
  const float* queue = (const float*)d_in[4];
  float* out = (float*)d_out;
  float* ws = (float*)d_ws;

  float* qInv = ws;                          // 6144
  float* S    = ws + 6144;                   // 16384
  float* lg0  = ws + 22528;                  // 16384
  float* mk   = ws + 38912;                  // 16384
  float* xr   = ws + 55296;                  // 16384 -> 71680
  int* count  = (int*)(ws + 71680);          // 1
  int* list   = (int*)(ws + 71696);          // 16384 -> 88080
  _Float16* QTf     = (_Float16*)(ws + 88320);    // NPIX*128 f16   (1048576 fl)
  _Float16* queueTf = (_Float16*)(ws + 1136896);  // 6144*128 f16   (393216 fl)
  _Float16* tgtTf   = (_Float16*)(ws + 1530112);  // NPIX*128 f16   (1048576 fl)
  _Float16* refTf   = (_Float16*)(ws + 2578688);  // NPIX*128 f16   (1048576 fl)

  // JAX: k1, k2 = split(key(1234))
  uint32_t b0o0, b0o1, b1o0, b1o1;
  threefry2x32(0u, 1234u, 0u, 2u, &b0o0, &b0o1);
  threefry2x32(0u, 1234u, 1u, 3u, &b1o0, &b1o1);
  uint32_t k1a = b0o0, k1b = b1o0, k2a = b0o1, k2b = b1o1;

  k_transpose<<<dim3(HWFM / 32, CFM / 32, 4), dim3(32, 8), 0, stream>>>(ref, tgt, refTf, tgtTf);
  k_qtrans<<<dim3(KQP / 32, CFM / 32), dim3(32, 8), 0, stream>>>(queue, queueTf);
  k_qnorms<<<dim3(KQP / 256), dim3(256), 0, stream>>>(queue, qInv);
  k_prelude<<<dim3(NPIX / 4), dim3(256), 0, stream>>>(tl, tr, refTf, tgtTf, QTf, S, lg0, mk, xr);
  k_compact<<<dim3(1), dim3(1024), 0, stream>>>(mk, count, list);
  k_negatives_mfma<<<dim3(NPIX / 4), dim3(256), 0, stream>>>(QTf, tgtTf, xr, S, count, list, k1a, k1b, k2a, k2b);
  k_gemm_mfma<<<dim3(8, NPIX / 64), dim3(256), 0, stream>>>(QTf, queueTf, qInv, S, count, list);
  k_finalize<<<dim3(1), dim3(1024), 0, stream>>>(S, lg0, mk, out);
}

// Round 8
// 164.454 us; speedup vs baseline: 5.6551x; 1.1310x over previous
//
#include <hip/hip_runtime.h>
#include <stdint.h>
#include <math.h>

#define HFM 64
#define WFM 128
#define CFM 128
#define BN 2
#define HWFM (HFM*WFM)          // 8192
#define NPIX (BN*HWFM)          // 16384
#define KQ 6000
#define KQP 6144                // padded to 48*128 (rows 6000..6143 zero)
#define NNEG 60
#define NE (NPIX*NNEG)          // 983040
#define EHALF_U 491520u
#define MSHIFT 15.0f

typedef _Float16 f16_8 __attribute__((ext_vector_type(8)));
typedef _Float16 f16_2 __attribute__((ext_vector_type(2)));
typedef float f32_4 __attribute__((ext_vector_type(4)));

// ---------------- JAX threefry2x32 (bit-exact) ----------------
__host__ __device__ __forceinline__ void threefry2x32(uint32_t k0, uint32_t k1,
                                                      uint32_t x0, uint32_t x1,
                                                      uint32_t* o0, uint32_t* o1) {
  uint32_t ks2 = k0 ^ k1 ^ 0x1BD11BDAu;
  x0 += k0; x1 += k1;
#define TFR(r) { x0 += x1; x1 = (x1 << (r)) | (x1 >> (32 - (r))); x1 ^= x0; }
  TFR(13) TFR(15) TFR(26) TFR(6)
  x0 += k1;  x1 += ks2 + 1u;
  TFR(17) TFR(29) TFR(16) TFR(24)
  x0 += ks2; x1 += k0 + 2u;
  TFR(13) TFR(15) TFR(26) TFR(6)
  x0 += k0;  x1 += k1 + 3u;
  TFR(17) TFR(29) TFR(16) TFR(24)
  x0 += k1;  x1 += ks2 + 4u;
  TFR(13) TFR(15) TFR(26) TFR(6)
  x0 += ks2; x1 += k0 + 5u;
#undef TFR
  *o0 = x0; *o1 = x1;
}

// grid_sample coordinate helper (reference op order)
__device__ __forceinline__ void gs_coord(float t, float halfdim, float maxc,
                                         int* i0, int* i1, float* w) {
  float g = 2.0f * t - 1.0f;
  float x = (g + 1.0f) * halfdim - 0.5f;
  x = fminf(fmaxf(x, 0.0f), maxc);
  float f = floorf(x);
  *i0 = (int)f;
  *w = x - f;
  *i1 = (int)fminf(f + 1.0f, maxc);
}

// ref [b,c,hw] -> refTf f16 [b,hw,c];  tgt [b,c,hw] -> tgtTf f16 [b,hw,c]
__global__ void k_transpose(const float* __restrict__ ref, const float* __restrict__ tgt,
                            _Float16* __restrict__ refTf, _Float16* __restrict__ tgtTf) {
  __shared__ float tile[32][33];
  int z = blockIdx.z;
  int arr = z >> 1, b = z & 1;
  const float* src = (arr == 0 ? ref : tgt) + (size_t)b * CFM * HWFM;
  _Float16* dst = (arr == 0 ? refTf : tgtTf) + (size_t)b * HWFM * CFM;
  int x0 = blockIdx.x * 32;   // hw
  int y0 = blockIdx.y * 32;   // c
  int tx = threadIdx.x, ty = threadIdx.y;
#pragma unroll
  for (int i = 0; i < 32; i += 8)
    tile[ty + i][tx] = src[(size_t)(y0 + ty + i) * HWFM + x0 + tx];
  __syncthreads();
#pragma unroll
  for (int i = 0; i < 32; i += 8)
    dst[(size_t)(x0 + ty + i) * CFM + (y0 + tx)] = (_Float16)tile[tx][ty + i];
}

// transpose queue [128][6000] fp32 -> [6144][128] f16 (rows 6000..6143 zero)
__global__ void k_qtrans(const float* __restrict__ queue, _Float16* __restrict__ queueTf) {
  __shared__ float tile[32][33];
  int n0 = blockIdx.x * 32;   // queue col
  int c0 = blockIdx.y * 32;   // channel
  int tx = threadIdx.x, ty = threadIdx.y;
#pragma unroll
  for (int i = 0; i < 32; i += 8) {
    int n = n0 + tx;
    tile[ty + i][tx] = (n < KQ) ? queue[(size_t)(c0 + ty + i) * KQ + n] : 0.0f;
  }
  __syncthreads();
#pragma unroll
  for (int i = 0; i < 32; i += 8)
    queueTf[(size_t)(n0 + ty + i) * CFM + (c0 + tx)] = (_Float16)tile[tx][ty + i];
}

// queue column inv-norms (zero for pad columns)
__global__ void k_qnorms(const float* __restrict__ queue, float* __restrict__ qInv) {
  int k = blockIdx.x * 256 + threadIdx.x;
  if (k >= KQP) return;
  if (k >= KQ) { qInv[k] = 0.0f; return; }
  float ss = 0.0f;
  for (int c = 0; c < CFM; c++) { float v = queue[c * KQ + k]; ss += v * v; }
  qInv[k] = 1.0f / fmaxf(sqrtf(ss), 1e-12f);
}

// per-(batch,x) column stats over rows y=0,1 of tgtTf:
// stats[(b*128+x)*8 + {n00,n01,n11,c00,c01,c10,c11,pad}]
// cXY = dot(Cx_row[x], Cy_row[min(x+1,127)])
__global__ __launch_bounds__(64) void k_colstats(const _Float16* __restrict__ tgtTf,
                                                 float* __restrict__ stats) {
  int b = blockIdx.x >> 7, x = blockIdx.x & 127;
  int xp = min(x + 1, 127);
  int lane = threadIdx.x;
  int c2 = lane * 2;
  int base = b * HWFM;
  f16_2 c0  = *(const f16_2*)(tgtTf + (size_t)(base + x) * CFM + c2);
  f16_2 c1  = *(const f16_2*)(tgtTf + (size_t)(base + WFM + x) * CFM + c2);
  f16_2 c0p = *(const f16_2*)(tgtTf + (size_t)(base + xp) * CFM + c2);
  f16_2 c1p = *(const f16_2*)(tgtTf + (size_t)(base + WFM + xp) * CFM + c2);
  float a0 = (float)c0[0], a1 = (float)c0[1];
  float b0 = (float)c1[0], b1 = (float)c1[1];
  float p0 = (float)c0p[0], p1 = (float)c0p[1];
  float q0 = (float)c1p[0], q1 = (float)c1p[1];
  float s[7];
  s[0] = a0 * a0 + a1 * a1;   // n00
  s[1] = a0 * b0 + a1 * b1;   // n01
  s[2] = b0 * b0 + b1 * b1;   // n11
  s[3] = a0 * p0 + a1 * p1;   // c00
  s[4] = a0 * q0 + a1 * q1;   // c01
  s[5] = b0 * p0 + b1 * p1;   // c10
  s[6] = b0 * q0 + b1 * q1;   // c11
#pragma unroll
  for (int o = 32; o; o >>= 1)
#pragma unroll
    for (int k = 0; k < 7; k++) s[k] += __shfl_xor(s[k], o, 64);
  if (lane == 0) {
    float* st = stats + (size_t)(b * 128 + x) * 8;
#pragma unroll
    for (int k = 0; k < 7; k++) st[k] = s[k];
    st[7] = 0.0f;
  }
}

// per pixel (wave-per-pixel): mask; if unmasked: fused query normalize,
// positive dot, l_pos, xr, S store. NO global atomics (compaction is separate).
__global__ __launch_bounds__(256) void k_prelude(
    const float* __restrict__ target_l, const float* __restrict__ target_r,
    const _Float16* __restrict__ refTf, const _Float16* __restrict__ tgtTf,
    _Float16* __restrict__ QTf,
    float* __restrict__ S, float* __restrict__ logit0,
    float* __restrict__ maskArr, float* __restrict__ xr) {
  int tid = threadIdx.x;
  int wave = tid >> 6, lane = tid & 63;
  int p = blockIdx.x * 4 + wave;
  int b = p >> 13;
  int rem = p & (HWFM - 1);
  int i = rem >> 7, j = rem & 127;
  const float stepx = 1.0f / 127.0f, stepy = 1.0f / 63.0f;
  float xb = (j == 127) ? 1.0f : j * stepx;
  float yb = (i == 63) ? 1.0f : i * stepy;
  const float* tl = target_l + (size_t)b * 256 * 512;
  const float* tr = target_r + (size_t)b * 256 * 512;

  int c2 = lane * 2;
  f16_2 q2 = *(const f16_2*)(refTf + (size_t)p * CFM + c2);

  float dl = tl[(4 * i) * 512 + 4 * j] * 0.25f;   // broadcast load

  int y0i, y1i; float wy;
  gs_coord(yb, 32.0f, 63.0f, &y0i, &y1i, &wy);
  float t = xb - dl * (1.0f / 128.0f);
  int x0i, x1i; float wx;
  gs_coord(t, 64.0f, 127.0f, &x0i, &x1i, &wx);

  int bo = b * HWFM;
  f16_2 a2 = *(const f16_2*)(tgtTf + (size_t)(bo + y0i * WFM + x0i) * CFM + c2);
  f16_2 b2 = *(const f16_2*)(tgtTf + (size_t)(bo + y0i * WFM + x1i) * CFM + c2);
  f16_2 cc2 = *(const f16_2*)(tgtTf + (size_t)(bo + y1i * WFM + x0i) * CFM + c2);
  f16_2 d2 = *(const f16_2*)(tgtTf + (size_t)(bo + y1i * WFM + x1i) * CFM + c2);

  auto innerv = [&](int y, int x) -> float {
    float xbx = (x == 127) ? 1.0f : x * stepx;
    float drv = tr[(4 * y) * 512 + 4 * x] * 0.25f;  // broadcast load
    float ti = xbx + drv * (1.0f / 128.0f);
    float g = 2.0f * ti - 1.0f;
    float ix2 = fminf(fmaxf((g + 1.0f) * 64.0f - 0.5f, 0.0f), 127.0f);
    float x0f = floorf(ix2);
    float wxp = ix2 - x0f;
    float x1f = fminf(x0f + 1.0f, 127.0f);
    return x0f * (1.0f - wxp) + x1f * wxp;
  };
  float v00 = innerv(y0i, x0i), v01 = innerv(y0i, x1i);
  float v10 = innerv(y1i, x0i), v11 = innerv(y1i, x1i);
  float l2r2l = v00 * (1.0f - wx) * (1.0f - wy) + v01 * wx * (1.0f - wy)
              + v10 * (1.0f - wx) * wy + v11 * wx * wy;
  bool masko = fabsf((float)j - l2r2l) < 3.0f;
  bool mk = masko && (dl > 0.0f) && (t >= 0.0f);
  if (lane == 0) maskArr[p] = mk ? 1.0f : 0.0f;
  if (!mk) return;   // wave-uniform

  float w00 = (1.0f - wx) * (1.0f - wy), w01 = wx * (1.0f - wy);
  float w10 = (1.0f - wx) * wy,          w11 = wx * wy;
  float q0 = (float)q2[0], q1 = (float)q2[1];
  float v0 = w00 * (float)a2[0] + w01 * (float)b2[0] + w10 * (float)cc2[0] + w11 * (float)d2[0];
  float v1 = w00 * (float)a2[1] + w01 * (float)b2[1] + w10 * (float)cc2[1] + w11 * (float)d2[1];

  float s0 = q0 * q0 + q1 * q1;
  float s1 = q0 * v0 + q1 * v1;
  float s2 = v0 * v0 + v1 * v1;
#pragma unroll
  for (int o = 32; o; o >>= 1) {
    s0 += __shfl_xor(s0, o, 64);
    s1 += __shfl_xor(s1, o, 64);
    s2 += __shfl_xor(s2, o, 64);
  }
  float inv = 1.0f / fmaxf(sqrtf(s0), 1e-12f);
  f16_2 qw; qw[0] = (_Float16)(q0 * inv); qw[1] = (_Float16)(q1 * inv);
  *(f16_2*)(QTf + (size_t)p * CFM + c2) = qw;
  if (lane == 0) {
    float lpos = (s1 * inv) / fmaxf(sqrtf(s2), 1e-12f);
    float lg0 = lpos / 0.07f;
    logit0[p] = lg0;
    xr[p] = t * 128.0f;
    S[p] = expf(lg0 - MSHIFT);   // first writer; later kernels atomicAdd
  }
}

// single-block ballot + prefix-scan compaction (ascending pixel order)
__global__ __launch_bounds__(1024) void k_compact(const float* __restrict__ maskArr,
                                                  int* __restrict__ count,
                                                  int* __restrict__ list) {
  int tid = threadIdx.x;             // 0..1023, each handles 16 consecutive pixels
  int lane = tid & 63, wave = tid >> 6;
  int base_p = tid * 16;
  const float4* m4 = (const float4*)(maskArr + base_p);
  float4 v[4];
#pragma unroll
  for (int k = 0; k < 4; k++) v[k] = m4[k];
  unsigned int bits = 0;
#pragma unroll
  for (int k = 0; k < 4; k++) {
    if (v[k].x > 0.0f) bits |= 1u << (4 * k + 0);
    if (v[k].y > 0.0f) bits |= 1u << (4 * k + 1);
    if (v[k].z > 0.0f) bits |= 1u << (4 * k + 2);
    if (v[k].w > 0.0f) bits |= 1u << (4 * k + 3);
  }
  int m = __popc(bits);
  int scan = m;
#pragma unroll
  for (int off = 1; off < 64; off <<= 1) {
    int n = __shfl_up(scan, off, 64);
    if (lane >= off) scan += n;
  }
  __shared__ int wsum[16];
  if (lane == 63) wsum[wave] = scan;
  __syncthreads();
  int wbase = 0;
  for (int w = 0; w < wave; w++) wbase += wsum[w];
  int idx = wbase + scan - m;
#pragma unroll
  for (int k = 0; k < 16; k++) {
    if (bits & (1u << k)) list[idx++] = base_p + k;
  }
  if (tid == 1023) *count = idx;
}

// -------- D-GEMM: D[slot][x] = dot(C_{y}[x], q_slot) for y=0 (cols 0..127)
// and y=1 (cols 128..255), via MFMA. B rows are tgtTf rows directly.
__global__ __launch_bounds__(256) void k_dgemm(
    const _Float16* __restrict__ QTf, const _Float16* __restrict__ tgtTf,
    float* __restrict__ D,
    const int* __restrict__ count, const int* __restrict__ list) {
  int tid = threadIdx.x;
  int cnt = *count;
  int pblk = blockIdx.x * 64;
  if (pblk >= cnt) return;
  int wave = tid >> 6, lane = tid & 63;
  int quad = lane >> 4, l16 = lane & 15;
  int wm = wave >> 1, wn = wave & 1;
  int p0 = pblk + wm * 32;

  __shared__ int pb[64];   // batch of each block row
  if (tid < 64) pb[tid] = list[min(pblk + tid, cnt - 1)] >> 13;
  __syncthreads();

  int prow[2];
#pragma unroll
  for (int mt = 0; mt < 2; mt++)
    prow[mt] = list[min(p0 + mt * 16 + l16, cnt - 1)];

  f16_8 Af[2][4];
#pragma unroll
  for (int mt = 0; mt < 2; mt++) {
    const _Float16* arow = QTf + (size_t)prow[mt] * CFM + quad * 8;
#pragma unroll
    for (int ks = 0; ks < 4; ks++)
      Af[mt][ks] = *(const f16_8*)(arow + ks * 32);
  }

  // 4 chunks of 128 cols: cols 0..255 -> tgtTf rows 0..255 (b0),
  // cols 256..511 -> tgtTf rows 8192..8447 (b1)
#pragma unroll
  for (int ic = 0; ic < 4; ic++) {
    int colbase = ic * 128;
    int rowbase = (ic < 2) ? ic * 128 : (HWFM + (ic - 2) * 128);
    f16_8 Bf[4][4];
    const _Float16* brow = tgtTf + (size_t)(rowbase + wn * 64 + l16) * CFM + quad * 8;
#pragma unroll
    for (int nt = 0; nt < 4; nt++)
#pragma unroll
      for (int ks = 0; ks < 4; ks++)
        Bf[nt][ks] = *(const f16_8*)(brow + (size_t)nt * 16 * CFM + ks * 32);

    f32_4 acc[2][4];
#pragma unroll
    for (int mt = 0; mt < 2; mt++)
#pragma unroll
      for (int nt = 0; nt < 4; nt++)
        acc[mt][nt] = (f32_4){0.0f, 0.0f, 0.0f, 0.0f};
#pragma unroll
    for (int ks = 0; ks < 4; ks++)
#pragma unroll
      for (int mt = 0; mt < 2; mt++)
#pragma unroll
        for (int nt = 0; nt < 4; nt++)
          acc[mt][nt] = __builtin_amdgcn_mfma_f32_16x16x32_f16(Af[mt][ks], Bf[nt][ks], acc[mt][nt], 0, 0, 0);

    // store: row pixel's batch selects which 256-col half it keeps
#pragma unroll
    for (int mt = 0; mt < 2; mt++)
#pragma unroll
      for (int nt = 0; nt < 4; nt++)
#pragma unroll
        for (int r = 0; r < 4; r++) {
          int rowloc = wm * 32 + mt * 16 + quad * 4 + r;
          int col = colbase + wn * 64 + nt * 16 + l16;
          if ((col >> 8) == pb[rowloc])
            D[(size_t)(pblk + rowloc) * 256 + (col & 255)] = acc[mt][nt][r];
        }
  }
}

// -------- negatives: wave-per-pixel, scalar via D + stats decomposition ----
__global__ __launch_bounds__(256) void k_negatives_lite(
    const float* __restrict__ D, const float* __restrict__ stats,
    const float* __restrict__ xr, float* __restrict__ S,
    const int* __restrict__ count, const int* __restrict__ list,
    uint32_t k1a, uint32_t k1b, uint32_t k2a, uint32_t k2b) {
  int tid = threadIdx.x;
  int wave = tid >> 6, lane = tid & 63;
  int cnt = *count;
  int slot = blockIdx.x * 4 + wave;
  if (slot >= cnt) return;
  int p = list[slot];
  int b = p >> 13;
  float esum = 0.0f;
  if (lane < NNEG) {
    uint32_t e = (uint32_t)(p * NNEG + lane);
    uint32_t h0, h1;
    threefry2x32(k1a, k1b, e, e + (uint32_t)NE, &h0, &h1);
    uint32_t off = ((h0 % 24u) * 16u + (h1 % 24u)) % 24u;
    float mag = (float)(1u + off);
    uint32_t ub;
    {
      uint32_t a, bm;
      if (e < EHALF_U) { threefry2x32(k2a, k2b, e, e + EHALF_U, &a, &bm); ub = a; }
      else             { threefry2x32(k2a, k2b, e - EHALF_U, e, &a, &bm); ub = bm; }
    }
    float u = __uint_as_float((ub >> 9) | 0x3F800000u) - 1.0f;
    float sg = (u > 0.5f) ? 1.0f : ((u < 0.5f) ? -1.0f : 0.0f);

    float v = xr[p] + mag * sg;
    float r = fmodf(v, 128.0f);
    if (r < 0.0f) r += 128.0f;
    float fx = r * (1.0f / 128.0f);
    float fy = fx * (1.0f / 64.0f);
    int x0i, x1i, y0i, y1i; float wx, wy;
    gs_coord(fx, 64.0f, 127.0f, &x0i, &x1i, &wx);
    gs_coord(fy, 32.0f, 63.0f, &y0i, &y1i, &wy);   // y0=0,y1=1 always

    const float* Dp = D + (size_t)slot * 256;
    float d00 = Dp[x0i], d01 = Dp[x1i];
    float d10 = Dp[128 + x0i], d11 = Dp[128 + x1i];
    float u0 = 1.0f - wy, u1 = wy;
    float dv0 = u0 * d00 + u1 * d10;
    float dv1 = u0 * d01 + u1 * d11;
    float dot = (1.0f - wx) * dv0 + wx * dv1;

    const float* st0 = stats + (size_t)(b * 128 + x0i) * 8;
    const float* st1 = stats + (size_t)(b * 128 + x1i) * 8;
    float4 sa = *(const float4*)st0;        // n00,n01,n11,c00
    float4 sb = *(const float4*)(st0 + 4);  // c01,c10,c11,pad
    float4 sc = *(const float4*)st1;        // n00,n01,n11,-
    float a0 = u0 * u0, a1 = u0 * u1, a2 = u1 * u1;
    float nB0 = a0 * sa.x + 2.0f * a1 * sa.y + a2 * sa.z;
    float nB1 = a0 * sc.x + 2.0f * a1 * sc.y + a2 * sc.z;
    float cB  = a0 * sa.w + a1 * (sb.x + sb.y) + a2 * sb.z;
    float wx0 = 1.0f - wx;
    float nsq = wx0 * wx0 * nB0 + 2.0f * wx * wx0 * cB + wx * wx * nB1;
    float ln = dot / fmaxf(sqrtf(fmaxf(nsq, 0.0f)), 1e-12f);
    esum = __expf(ln * (1.0f / 0.07f) - MSHIFT);
  }
#pragma unroll
  for (int o = 32; o; o >>= 1) esum += __shfl_xor(esum, o, 64);
  if (lane == 0) atomicAdd(&S[p], esum);
}

// -------- MFMA l_q GEMM over compacted rows, fused with exp-sum --------
__global__ __launch_bounds__(256) void k_gemm_mfma(
    const _Float16* __restrict__ QTf,     // [NPIX][128]
    const _Float16* __restrict__ queueTf, // [6144][128], rows >=6000 zero
    const float* __restrict__ qInv,       // [6144], zero for pad
    float* __restrict__ S,
    const int* __restrict__ count, const int* __restrict__ list) {
  __shared__ float Srow[64];
  int tid = threadIdx.x;
  int cnt = *count;
  if ((int)(blockIdx.y * 64) >= cnt) return;
  int wave = tid >> 6;
  int lane = tid & 63;
  int quad = lane >> 4;
  int l16 = lane & 15;
  int wm = wave >> 1;
  int wn = wave & 1;
  int p0 = blockIdx.y * 64 + wm * 32;

  if (tid < 64) Srow[tid] = 0.0f;

  int prow[2];
#pragma unroll
  for (int mt = 0; mt < 2; mt++)
    prow[mt] = list[min(p0 + mt * 16 + l16, cnt - 1)];

  f16_8 Af[2][4];
#pragma unroll
  for (int mt = 0; mt < 2; mt++) {
    const _Float16* arow = QTf + (size_t)prow[mt] * CFM + quad * 8;
#pragma unroll
    for (int ks = 0; ks < 4; ks++)
      Af[mt][ks] = *(const f16_8*)(arow + ks * 32);
  }

  float mrow[2][4];
#pragma unroll
  for (int mt = 0; mt < 2; mt++)
#pragma unroll
    for (int r = 0; r < 4; r++)
      mrow[mt][r] = (p0 + mt * 16 + quad * 4 + r < cnt) ? (1.0f / 0.07f) : 0.0f;

  float rowsum[2][4] = {{0.0f,0.0f,0.0f,0.0f},{0.0f,0.0f,0.0f,0.0f}};

  for (int ic = 0; ic < 6; ic++) {
    int n0 = (blockIdx.x * 6 + ic) * 128 + wn * 64;

    f16_8 Bf[4][4];
    const _Float16* brow = queueTf + (size_t)(n0 + l16) * CFM + quad * 8;
#pragma unroll
    for (int nt = 0; nt < 4; nt++)
#pragma unroll
      for (int ks = 0; ks < 4; ks++)
        Bf[nt][ks] = *(const f16_8*)(brow + (size_t)nt * 16 * CFM + ks * 32);

    f32_4 acc[2][4];
#pragma unroll
    for (int mt = 0; mt < 2; mt++)
#pragma unroll
      for (int nt = 0; nt < 4; nt++)
        acc[mt][nt] = (f32_4){0.0f, 0.0f, 0.0f, 0.0f};

#pragma unroll
    for (int ks = 0; ks < 4; ks++)
#pragma unroll
      for (int mt = 0; mt < 2; mt++)
#pragma unroll
        for (int nt = 0; nt < 4; nt++)
          acc[mt][nt] = __builtin_amdgcn_mfma_f32_16x16x32_f16(Af[mt][ks], Bf[nt][ks], acc[mt][nt], 0, 0, 0);

#pragma unroll
    for (int nt = 0; nt < 4; nt++) {
      int n = n0 + nt * 16 + l16;
      bool valid = n < KQ;
      float qi = qInv[n];
#pragma unroll
      for (int mt = 0; mt < 2; mt++)
#pragma unroll
        for (int r = 0; r < 4; r++) {
          float lg = acc[mt][nt][r] * qi * mrow[mt][r];
          float ev = valid ? __expf(lg - MSHIFT) : 0.0f;
          rowsum[mt][r] += ev;
        }
    }
  }

#pragma unroll
  for (int mt = 0; mt < 2; mt++)
#pragma unroll
    for (int r = 0; r < 4; r++) {
      float vv = rowsum[mt][r];
      vv += __shfl_xor(vv, 1);
      vv += __shfl_xor(vv, 2);
      vv += __shfl_xor(vv, 4);
      vv += __shfl_xor(vv, 8);
      rowsum[mt][r] = vv;
    }
  __syncthreads();
  if (l16 == 0) {
#pragma unroll
    for (int mt = 0; mt < 2; mt++)
#pragma unroll
      for (int r = 0; r < 4; r++)
        atomicAdd(&Srow[wm * 32 + mt * 16 + quad * 4 + r], rowsum[mt][r]);
  }
  __syncthreads();
  if (tid < 64) {
    int pr = blockIdx.y * 64 + tid;
    if (pr < cnt) atomicAdd(&S[list[pr]], Srow[tid]);
  }
}

__global__ __launch_bounds__(1024) void k_finalize(
    const float* __restrict__ S, const float* __restrict__ logit0,
    const float* __restrict__ maskArr, float* __restrict__ out) {
  int tid = threadIdx.x;
  const float cmask = logf(6061.0f);
  double acc = 0.0;
  for (int p = tid; p < NPIX; p += 1024) {
    float term = (maskArr[p] > 0.0f) ? (logf(S[p]) + MSHIFT - logit0[p]) : cmask;
    acc += (double)term;
  }
#pragma unroll
  for (int off = 32; off; off >>= 1) acc += __shfl_down(acc, off, 64);
  __shared__ double sd[16];
  if ((tid & 63) == 0) sd[tid >> 6] = acc;
  __syncthreads();
  if (tid == 0) {
    double tot = 0.0;
    for (int w = 0; w < 16; w++) tot += sd[w];
    out[0] = (float)(tot / (double)NPIX);
  }
}

extern "C" void kernel_launch(void* const* d_in, const int* in_sizes, int n_in,
                              void* d_out, int out_size, void* d_ws, size_t ws_size,
                              hipStream_t stream) {
  const float* ref   = (const float*)d_in[0];
  const float* tgt   = (const float*)d_in[1];
  const float* tl    = (const float*)d_in[2];
  const float* tr    = (const float*)d_in[3];
  const float* queue = (const float*)d_in[4];
  float* out = (float*)d_out;
  float* ws = (float*)d_ws;

  float* qInv = ws;                          // 6144
  float* S    = ws + 6144;                   // 16384
  float* lg0  = ws + 22528;                  // 16384
  float* mk   = ws + 38912;                  // 16384
  float* xr   = ws + 55296;                  // 16384 -> 71680
  int* count  = (int*)(ws + 71680);          // 1
  int* list   = (int*)(ws + 71696);          // 16384 -> 88080
  _Float16* QTf     = (_Float16*)(ws + 88320);    // NPIX*128 f16   (1048576 fl)
  _Float16* queueTf = (_Float16*)(ws + 1136896);  // 6144*128 f16   (393216 fl)
  _Float16* tgtTf   = (_Float16*)(ws + 1530112);  // NPIX*128 f16   (1048576 fl)
  _Float16* refTf   = (_Float16*)(ws + 2578688);  // NPIX*128 f16   (1048576 fl)
  float* stats = ws + 3627264;                    // 2*128*8 = 2048 -> 3629312
  float* D     = ws + 3629312;                    // NPIX*256 f32 = 4194304 fl

  // JAX: k1, k2 = split(key(1234))
  uint32_t b0o0, b0o1, b1o0, b1o1;
  threefry2x32(0u, 1234u, 0u, 2u, &b0o0, &b0o1);
  threefry2x32(0u, 1234u, 1u, 3u, &b1o0, &b1o1);
  uint32_t k1a = b0o0, k1b = b1o0, k2a = b0o1, k2b = b1o1;

  k_transpose<<<dim3(HWFM / 32, CFM / 32, 4), dim3(32, 8), 0, stream>>>(ref, tgt, refTf, tgtTf);
  k_qtrans<<<dim3(KQP / 32, CFM / 32), dim3(32, 8), 0, stream>>>(queue, queueTf);
  k_qnorms<<<dim3(KQP / 256), dim3(256), 0, stream>>>(queue, qInv);
  k_colstats<<<dim3(256), dim3(64), 0, stream>>>(tgtTf, stats);
  k_prelude<<<dim3(NPIX / 4), dim3(256), 0, stream>>>(tl, tr, refTf, tgtTf, QTf, S, lg0, mk, xr);
  k_compact<<<dim3(1), dim3(1024), 0, stream>>>(mk, count, list);
  k_dgemm<<<dim3(NPIX / 64), dim3(256), 0, stream>>>(QTf, tgtTf, D, count, list);
  k_negatives_lite<<<dim3(NPIX / 4), dim3(256), 0, stream>>>(D, stats, xr, S, count, list, k1a, k1b, k2a, k2b);
  k_gemm_mfma<<<dim3(8, NPIX / 64), dim3(256), 0, stream>>>(QTf, queueTf, qInv, S, count, list);
  k_finalize<<<dim3(1), dim3(1024), 0, stream>>>(S, lg0, mk, out);
}